// Round 3
// baseline (255.607 us; speedup 1.0000x reference)
//
#include <hip/hip_runtime.h>
#include <stdint.h>

// Problem constants (from reference): B=8, T=4096, D=1024, H=32.
#define D_DIM 1024
#define T_DIM 4096
#define B_DIM 8
#define M_REAL (B_DIM * (T_DIM + 1))   // 32776 output rows
#define NBLK_M 129                      // ceil(M_REAL/256)
#define NWG (4 * NBLK_M)                // 516 blocks for main GEMM

typedef short short8 __attribute__((ext_vector_type(8)));   // 8 bf16 (4 VGPRs)
typedef float floatx4 __attribute__((ext_vector_type(4)));  // 4 fp32 acc

typedef const __attribute__((address_space(1))) void* gptr_t;
typedef __attribute__((address_space(3))) void* lptr_t;

__device__ __forceinline__ ushort f2bf(float f) {
  union { float f; uint32_t u; } v; v.f = f;
  uint32_t r = v.u + 0x7FFF + ((v.u >> 16) & 1);  // RNE
  return (ushort)(r >> 16);
}

// ---------------------------------------------------------------------------
// Main GEMM: C[m,n] = sum_k A[m,k]*B[n,k] + bias[n].  A: [M_REAL(+clamp)]x1024
// bf16, B: 1024x1024 bf16 (row-major, K contiguous), C fp32.
// 256x256 tile, BK=32, 8 waves (2M x 4N), per-wave 128x64 output.
// 2-phase double-buffered: stage tile t+1 BEFORE compute of tile t; one
// __syncthreads per K-step (drains vmcnt after ~600cyc of MFMA cover).
// LDS 64KB static -> 2 blocks/CU co-resident (cross-block stall overlap).
// ---------------------------------------------------------------------------
__global__ __launch_bounds__(512, 2) void gemm256_kernel(
    const ushort* __restrict__ A, const ushort* __restrict__ Bm,
    float* __restrict__ C, const float* __restrict__ bias)
{
  __shared__ ushort As[2][256][32];   // 32 KB
  __shared__ ushort Bs[2][256][32];   // 32 KB
  const int tid  = threadIdx.x;
  const int wave = tid >> 6;
  const int lane = tid & 63;
  const int wm = wave >> 2, wn = wave & 3;     // 2 x 4 wave grid
  const int l15 = lane & 15, lhi = lane >> 4;

  // m204 bijective XCD swizzle, nwg=516: q=64, r=4.
  const int bid = blockIdx.x;
  const int xcd = bid & 7;
  const int wg  = (xcd < 4 ? xcd * 65 : 260 + (xcd - 4) * 64) + (bid >> 3);
  const int n0 = (wg & 3) * 256;
  const int m0 = (wg >> 2) * 256;

  // Staging map: per K-step the A tile is 256x32 bf16 (16KB) = 2 rounds of
  // 512thr x 16B. chunk = q*512 + tid; row = chunk>>2; k8 = (chunk&3)*8.
  // A-rows beyond M_REAL are clamped (their outputs are guarded away).
  const int srow = tid >> 2;          // 0..127
  const int sk8  = (tid & 3) * 8;     // 0,8,16,24
  const ushort* Aq[2]; const ushort* Bq[2];
#pragma unroll
  for (int q = 0; q < 2; ++q) {
    int ar = m0 + q * 128 + srow; if (ar > M_REAL - 1) ar = M_REAL - 1;
    Aq[q] = A  + (size_t)ar * D_DIM + sk8;
    Bq[q] = Bm + (size_t)(n0 + q * 128 + srow) * D_DIM + sk8;
  }

  floatx4 acc[8][4] = {};

  // Prologue: stage K-tile 0 into buffer 0.
#pragma unroll
  for (int q = 0; q < 2; ++q) {
    __builtin_amdgcn_global_load_lds((gptr_t)(Aq[q]),
        (lptr_t)((char*)&As[0][0][0] + (q * 512 + wave * 64) * 16), 16, 0, 0);
    __builtin_amdgcn_global_load_lds((gptr_t)(Bq[q]),
        (lptr_t)((char*)&Bs[0][0][0] + (q * 512 + wave * 64) * 16), 16, 0, 0);
  }
  __syncthreads();

  int buf = 0;
  for (int t = 0; t < 32; ++t) {          // K = 1024 = 32 * BK
    if (t < 31) {
      const int k0 = (t + 1) * 32;
#pragma unroll
      for (int q = 0; q < 2; ++q) {
        __builtin_amdgcn_global_load_lds((gptr_t)(Aq[q] + k0),
            (lptr_t)((char*)&As[buf ^ 1][0][0] + (q * 512 + wave * 64) * 16), 16, 0, 0);
        __builtin_amdgcn_global_load_lds((gptr_t)(Bq[q] + k0),
            (lptr_t)((char*)&Bs[buf ^ 1][0][0] + (q * 512 + wave * 64) * 16), 16, 0, 0);
      }
    }
    short8 a[8], b[4];
#pragma unroll
    for (int m = 0; m < 8; ++m)
      a[m] = *(const short8*)(&As[buf][wm * 128 + m * 16 + l15][lhi * 8]);
#pragma unroll
    for (int n = 0; n < 4; ++n)
      b[n] = *(const short8*)(&Bs[buf][wn * 64 + n * 16 + l15][lhi * 8]);
#pragma unroll
    for (int m = 0; m < 8; ++m)
#pragma unroll
      for (int n = 0; n < 4; ++n)
        acc[m][n] = __builtin_amdgcn_mfma_f32_16x16x32_bf16(
            a[m], b[n], acc[m][n], 0, 0, 0);
    __syncthreads();   // drains this wave's prefetch loads + syncs buffer swap
    buf ^= 1;
  }

  // Epilogue. C/D layout: col = lane&15, row = (lane>>4)*4 + j.
#pragma unroll
  for (int m = 0; m < 8; ++m)
#pragma unroll
    for (int n = 0; n < 4; ++n) {
      const int gn = n0 + wn * 64 + n * 16 + l15;
      const float bia = bias[gn];
#pragma unroll
      for (int j = 0; j < 4; ++j) {
        const int gm = m0 + wm * 128 + m * 16 + lhi * 4 + j;
        if (gm < M_REAL) C[(size_t)gm * D_DIM + gn] = acc[m][n][j] + bia;
      }
    }
}

// ---------------------------------------------------------------------------
// Small GEMM for Wfused = Wo @ Wv (bf16 out): m97-style 128x128 tile, BK=64.
// Only 64 blocks / 2.1 GF -- not worth a bigger structure.
// ---------------------------------------------------------------------------
__global__ __launch_bounds__(256) void gemm_bt_kernel(
    const ushort* __restrict__ A, const ushort* __restrict__ Bm,
    ushort* __restrict__ Cb, int K, int N)
{
  __shared__ ushort As[128][64];   // 16 KB
  __shared__ ushort Bs[128][64];   // 16 KB
  const int tid  = threadIdx.x;
  const int wave = tid >> 6;
  const int lane = tid & 63;
  const int wm = wave >> 1, wn = wave & 1;
  const int n0 = blockIdx.x * 128, m0 = blockIdx.y * 128;
  const int l15 = lane & 15, lhi = lane >> 4;

  floatx4 acc[4][4] = {};

  const int srow = tid >> 3;
  const int sk8  = (tid & 7) * 8;
  const ushort* Ab = A  + (size_t)(m0 + srow) * K + sk8;
  const ushort* Bb = Bm + (size_t)(n0 + srow) * K + sk8;

  for (int k0 = 0; k0 < K; k0 += 64) {
#pragma unroll
    for (int q = 0; q < 4; ++q)
      __builtin_amdgcn_global_load_lds((gptr_t)(Ab + k0 + (size_t)q * 32 * K),
          (lptr_t)((char*)&As[0][0] + (q * 256 + wave * 64) * 16), 16, 0, 0);
#pragma unroll
    for (int q = 0; q < 4; ++q)
      __builtin_amdgcn_global_load_lds((gptr_t)(Bb + k0 + (size_t)q * 32 * K),
          (lptr_t)((char*)&Bs[0][0] + (q * 256 + wave * 64) * 16), 16, 0, 0);
    __syncthreads();

#pragma unroll
    for (int kk = 0; kk < 2; ++kk) {
      short8 af[4], bfr[4];
#pragma unroll
      for (int i = 0; i < 4; ++i) {
        af[i]  = *(const short8*)(&As[wm * 64 + i * 16 + l15][kk * 32 + lhi * 8]);
        bfr[i] = *(const short8*)(&Bs[wn * 64 + i * 16 + l15][kk * 32 + lhi * 8]);
      }
#pragma unroll
      for (int mi = 0; mi < 4; ++mi)
#pragma unroll
        for (int ni = 0; ni < 4; ++ni)
          acc[mi][ni] = __builtin_amdgcn_mfma_f32_16x16x32_bf16(
              af[mi], bfr[ni], acc[mi][ni], 0, 0, 0);
    }
    __syncthreads();
  }

#pragma unroll
  for (int mi = 0; mi < 4; ++mi)
#pragma unroll
    for (int ni = 0; ni < 4; ++ni) {
      const int gn = n0 + wn * 64 + ni * 16 + l15;
#pragma unroll
      for (int j = 0; j < 4; ++j) {
        const int gm = m0 + wm * 64 + mi * 16 + lhi * 4 + j;
        Cb[(size_t)gm * N + gn] = f2bf(acc[mi][ni][j]);
      }
    }
}

// ---------------------------------------------------------------------------
// Depthwise temporal conv -> s_bf16 [M_REAL][1024].
// s[b,t,:] = sum_{i=0}^{31} w[i] * x[b, t-32+i, :]   (x[neg] = 0), t in [0,4096].
// Stable descending recurrence: s[t-1] = r*s[t] + w0*x[t-33] - (w31*r)*x[t-1].
// TCH=32 t-steps per block -> 1032 blocks (~4/CU) so TLP hides latency.
// ---------------------------------------------------------------------------
#define TCH 32
__global__ __launch_bounds__(256) void conv_kernel(
    const float* __restrict__ x, const float* __restrict__ dw,
    ushort* __restrict__ S)
{
  const int b  = blockIdx.y;
  const int d4 = threadIdx.x;               // 0..255 (float4 columns)
  const int t0 = blockIdx.x * TCH;
  const int t_hi = min(t0 + TCH - 1, T_DIM);   // T_DIM = last valid t (4096)

  float w[32];
#pragma unroll
  for (int i = 0; i < 32; ++i) w[i] = dw[i];
  const float r    = w[1] / w[0];
  const float w0   = w[0];
  const float cr32 = w[31] * r;             // C * r^32

  const float4* xb = (const float4*)(x + (size_t)b * T_DIM * D_DIM) + d4;

  float sx = 0.f, sy = 0.f, sz = 0.f, swv = 0.f;
#pragma unroll
  for (int i = 0; i < 32; ++i) {
    const int idx = t_hi - 32 + i;
    if (idx >= 0) {
      float4 v = xb[(size_t)idx * 256];
      sx += w[i] * v.x; sy += w[i] * v.y; sz += w[i] * v.z; swv += w[i] * v.w;
    }
  }
  {
    ushort4 o = make_ushort4(f2bf(sx), f2bf(sy), f2bf(sz), f2bf(swv));
    *(ushort4*)(S + (size_t)(b * (T_DIM + 1) + t_hi) * D_DIM + d4 * 4) = o;
  }
  for (int t = t_hi; t > t0; --t) {
    float ax = 0.f, ay = 0.f, az = 0.f, aw = 0.f;
    const int ia = t - 33;
    if (ia >= 0) {
      float4 v = xb[(size_t)ia * 256];
      ax = v.x; ay = v.y; az = v.z; aw = v.w;
    }
    const float4 vc = xb[(size_t)(t - 1) * 256];
    sx  = r * sx  + w0 * ax - cr32 * vc.x;
    sy  = r * sy  + w0 * ay - cr32 * vc.y;
    sz  = r * sz  + w0 * az - cr32 * vc.z;
    swv = r * swv + w0 * aw - cr32 * vc.w;
    ushort4 o = make_ushort4(f2bf(sx), f2bf(sy), f2bf(sz), f2bf(swv));
    *(ushort4*)(S + (size_t)(b * (T_DIM + 1) + (t - 1)) * D_DIM + d4 * 4) = o;
  }
}

// Wo fp32 -> bf16 straight copy.
__global__ void convert_wo_kernel(const float* __restrict__ Wo, ushort* __restrict__ WoB) {
  const int i = blockIdx.x * 256 + threadIdx.x;      // float4 index
  const float4 v = ((const float4*)Wo)[i];
  ushort4 o = make_ushort4(f2bf(v.x), f2bf(v.y), f2bf(v.z), f2bf(v.w));
  *(ushort4*)(WoB + (size_t)i * 4) = o;
}

// Wv fp32 -> WvT bf16 (transpose via LDS 32x32 tile).
__global__ void transpose_wv_kernel(const float* __restrict__ Wv, ushort* __restrict__ WvT) {
  __shared__ float tile[32][33];
  const int tx = threadIdx.x;   // 0..31
  const int ty = threadIdx.y;   // 0..7
  const int c0 = blockIdx.x * 32;
  const int r0 = blockIdx.y * 32;
#pragma unroll
  for (int j = 0; j < 4; ++j)
    tile[ty + j * 8][tx] = Wv[(size_t)(r0 + ty + j * 8) * D_DIM + c0 + tx];
  __syncthreads();
#pragma unroll
  for (int j = 0; j < 4; ++j)
    WvT[(size_t)(c0 + ty + j * 8) * D_DIM + r0 + tx] = f2bf(tile[tx][ty + j * 8]);
}

// cvec[j] = sum(dw) * dot(Wo[j,:], bv) + bo[j].  One wave per j.
__global__ void bias_kernel(const float* __restrict__ Wo, const float* __restrict__ bv,
                            const float* __restrict__ bo, const float* __restrict__ dw,
                            float* __restrict__ cvec) {
  const int j    = blockIdx.x * 4 + (threadIdx.x >> 6);
  const int lane = threadIdx.x & 63;
  float sumw = 0.f;
#pragma unroll
  for (int i = 0; i < 32; ++i) sumw += dw[i];
  float s = 0.f;
  for (int k = lane; k < D_DIM; k += 64) s += Wo[(size_t)j * D_DIM + k] * bv[k];
#pragma unroll
  for (int off = 32; off; off >>= 1) s += __shfl_xor(s, off, 64);
  if (lane == 0) cvec[j] = sumw * s + bo[j];
}

// ---------------------------------------------------------------------------
extern "C" void kernel_launch(void* const* d_in, const int* in_sizes, int n_in,
                              void* d_out, int out_size, void* d_ws, size_t ws_size,
                              hipStream_t stream) {
  const float* x  = (const float*)d_in[0];
  const float* Wv = (const float*)d_in[1];
  const float* bv = (const float*)d_in[2];
  const float* Wo = (const float*)d_in[3];
  const float* bo = (const float*)d_in[4];
  const float* dw = (const float*)d_in[5];
  float* out = (float*)d_out;

  // Workspace layout (~73.4 MB total).
  char* ws = (char*)d_ws;
  ushort* S      = (ushort*)ws;                                  // M_REAL*1024 bf16
  ushort* WoB    = (ushort*)(ws + (size_t)M_REAL * D_DIM * 2);   // 1024^2 bf16
  ushort* WvT    = WoB + (size_t)D_DIM * D_DIM;                  // 1024^2 bf16
  ushort* Wfused = WvT + (size_t)D_DIM * D_DIM;                  // 1024^2 bf16
  float*  cvec   = (float*)(Wfused + (size_t)D_DIM * D_DIM);     // 1024 fp32

  // 1) Weight prep (all tiny).
  convert_wo_kernel<<<dim3(D_DIM * D_DIM / 1024), dim3(256), 0, stream>>>(Wo, WoB);
  transpose_wv_kernel<<<dim3(32, 32), dim3(32, 8), 0, stream>>>(Wv, WvT);
  bias_kernel<<<dim3(256), dim3(256), 0, stream>>>(Wo, bv, bo, dw, cvec);

  // 2) Wfused[j,k] = sum_p Wo[j,p] * Wv[p,k]  (row-major bf16).
  gemm_bt_kernel<<<dim3(8, 8), dim3(256), 0, stream>>>(
      WoB, WvT, Wfused, D_DIM, D_DIM);

  // 3) Temporal conv -> s bf16.
  conv_kernel<<<dim3((T_DIM / TCH) + 1, B_DIM), dim3(256), 0, stream>>>(x, dw, S);

  // 4) out = s @ Wfused^T + cvec  (256^2 tile, 2-phase dbuf, XCD-swizzled).
  gemm256_kernel<<<dim3(NWG), dim3(512), 0, stream>>>(S, Wfused, out, cvec);
}

// Round 4
// 234.716 us; speedup vs baseline: 1.0890x; 1.0890x over previous
//
#include <hip/hip_runtime.h>
#include <stdint.h>

// Problem constants (from reference): B=8, T=4096, D=1024, H=32.
#define D_DIM 1024
#define T_DIM 4096
#define B_DIM 8
#define M_REAL (B_DIM * (T_DIM + 1))   // 32776 output rows
#define NBLK_M 129                      // ceil(M_REAL/256)
#define NWG (4 * NBLK_M)                // 516 blocks for main GEMM

typedef short short8 __attribute__((ext_vector_type(8)));   // 8 bf16 (4 VGPRs)
typedef float floatx4 __attribute__((ext_vector_type(4)));  // 4 fp32 acc

typedef const __attribute__((address_space(1))) void* gptr_t;
typedef __attribute__((address_space(3))) void* lptr_t;

__device__ __forceinline__ ushort f2bf(float f) {
  union { float f; uint32_t u; } v; v.f = f;
  uint32_t r = v.u + 0x7FFF + ((v.u >> 16) & 1);  // RNE
  return (ushort)(r >> 16);
}

#define BARRIER()  asm volatile("s_barrier" ::: "memory")
#define WAIT_VM6() asm volatile("s_waitcnt vmcnt(6)" ::: "memory")
#define WAIT_VM0() asm volatile("s_waitcnt vmcnt(0)" ::: "memory")
// rule #18: sched_barrier(0) after lgkmcnt so MFMA can't hoist above the wait.
#define WAIT_LGKM0() do { asm volatile("s_waitcnt lgkmcnt(0)" ::: "memory"); \
                          __builtin_amdgcn_sched_barrier(0); } while (0)

// ---------------------------------------------------------------------------
// Main GEMM: C[m,n] = sum_k A[m,k]*B[n,k] + bias[n].  A,B bf16 row-major.
// 256x256 tile, BK=64, 8 waves (2M x 4N), per-wave 128x64 output.
// 8-phase-style schedule (T2+T3+T4+T5): 128KB LDS = 2 dbuf x {A,B} x 2 halves
// of [128][64] bf16 (16KB each). st_16x32 XOR swizzle (byte ^= ((byte>>9)&1)<<5)
// realized as linear LDS dest + pre-swizzled GLOBAL source + swizzled ds_read.
// Stage order per K-tile u: B0,B1,A0,A1 (sigma = 4u+ord), issued 6 half-tiles
// ahead: at phase (4u+q) stage sigma=4u+q+6. Certification: vmcnt(6)+barrier
// once per K-tile at phase 0 (3 newer half-tiles = 6 loads stay in flight).
// Race-freedom: each slot's new stage-issue is in a strictly later barrier
// region than the previous occupant's last ds_read (A halves last read phi3,
// overwritten at next K-tile's phi0/phi1; B halves last read phi0, overwritten
// at phi2/phi3 of the tile before reuse).
// ---------------------------------------------------------------------------
__global__ __launch_bounds__(512, 2) void gemm256_kernel(
    const ushort* __restrict__ A, const ushort* __restrict__ Bm,
    float* __restrict__ C, const float* __restrict__ bias)
{
  __shared__ char smem[131072];   // [A|B][buf][half] 16KB slots; B at +65536
  const int tid  = threadIdx.x;
  const int wave = tid >> 6;
  const int lane = tid & 63;
  const int wm = wave >> 2, wn = wave & 3;     // 2 x 4 wave grid
  const int l15 = lane & 15, lhi = lane >> 4;

  // m204 bijective XCD swizzle, nwg=516: q=64, r=4.
  const int bid = blockIdx.x;
  const int xcd = bid & 7;
  const int wg  = (xcd < 4 ? xcd * 65 : 260 + (xcd - 4) * 64) + (bid >> 3);
  const int n0 = (wg & 3) * 256;
  const int m0 = (wg >> 2) * 256;

  // Staging source map. Half-tile = [128 rows][64 cols] bf16 = 16KB = 1024
  // 16B-chunks. Thread tid stages chunks c=tid (j=0) and c=512+tid (j=1) to
  // LINEAR dest c*16. Pre-swizzle source: clog = c ^ (((c>>5)&1)<<1)
  // (chunk-level image of byte ^= ((byte>>9)&1)<<5). row=clog>>3, kelem=(clog&7)*8.
  const int clog = tid ^ (((tid >> 5) & 1) << 1);
  const int rowc = clog >> 3;          // 0..63 (j=1 adds 64)
  const int ke   = (clog & 7) * 8;

  const ushort* Asrc[2][2]; const ushort* Bsrc[2][2];   // [half][j], literal-indexed
#pragma unroll
  for (int h = 0; h < 2; ++h)
#pragma unroll
    for (int j = 0; j < 2; ++j) {
      int ar = m0 + h * 128 + rowc + j * 64; if (ar > M_REAL - 1) ar = M_REAL - 1;
      Asrc[h][j] = A  + (size_t)ar * D_DIM + ke;
      Bsrc[h][j] = Bm + (size_t)(n0 + h * 128 + rowc + j * 64) * D_DIM + ke;
    }

#define STAGE_A(H, U, BUF) do { \
  __builtin_amdgcn_global_load_lds((gptr_t)(Asrc[H][0] + (U) * 64), \
      (lptr_t)(smem + ((BUF) * 2 + (H)) * 16384 + wave * 1024), 16, 0, 0); \
  __builtin_amdgcn_global_load_lds((gptr_t)(Asrc[H][1] + (U) * 64), \
      (lptr_t)(smem + ((BUF) * 2 + (H)) * 16384 + 8192 + wave * 1024), 16, 0, 0); \
} while (0)
#define STAGE_B(H, U, BUF) do { \
  __builtin_amdgcn_global_load_lds((gptr_t)(Bsrc[H][0] + (U) * 64), \
      (lptr_t)(smem + 65536 + ((BUF) * 2 + (H)) * 16384 + wave * 1024), 16, 0, 0); \
  __builtin_amdgcn_global_load_lds((gptr_t)(Bsrc[H][1] + (U) * 64), \
      (lptr_t)(smem + 65536 + ((BUF) * 2 + (H)) * 16384 + 8192 + wave * 1024), 16, 0, 0); \
} while (0)

  short8 a[4];        // current-phase A frags
  short8 bfr[2][4];   // B frags, both k-slices, live across the K-tile
  floatx4 acc[8][4] = {};

// Swizzled ds_read of one frag: logical byte o within half-tile, phys = o^bit9->bit5.
#define LDA(MH, KK, BUF) do { \
  const char* _ab = smem + ((BUF) * 2 + wm) * 16384; \
  _Pragma("unroll") \
  for (int mp = 0; mp < 4; ++mp) { \
    int o = ((MH) * 64 + mp * 16 + l15) * 128 + (KK) * 64 + lhi * 16; \
    o ^= ((o >> 9) & 1) << 5; \
    a[mp] = *(const short8*)(_ab + o); \
  } } while (0)
#define LDB(KK, BUF) do { \
  const char* _bb = smem + 65536 + ((BUF) * 2 + (wn >> 1)) * 16384; \
  _Pragma("unroll") \
  for (int n = 0; n < 4; ++n) { \
    int o = ((wn & 1) * 64 + n * 16 + l15) * 128 + (KK) * 64 + lhi * 16; \
    o ^= ((o >> 9) & 1) << 5; \
    bfr[KK][n] = *(const short8*)(_bb + o); \
  } } while (0)

#define MFMA16(MH, KK) do { \
  _Pragma("unroll") \
  for (int mp = 0; mp < 4; ++mp) \
    _Pragma("unroll") \
    for (int n = 0; n < 4; ++n) \
      acc[(MH) * 4 + mp][n] = __builtin_amdgcn_mfma_f32_16x16x32_bf16( \
          a[mp], bfr[KK][n], acc[(MH) * 4 + mp][n], 0, 0, 0); \
} while (0)

#define COMPUTE(MH, KK) do { BARRIER(); WAIT_LGKM0(); \
  __builtin_amdgcn_s_setprio(1); MFMA16(MH, KK); __builtin_amdgcn_s_setprio(0); \
  BARRIER(); } while (0)

  // Prologue: stage sigma = 0..5 in order (K-tile0 B0,B1,A0,A1; K-tile1 B0,B1).
  STAGE_B(0, 0, 0); STAGE_B(1, 0, 0); STAGE_A(0, 0, 0); STAGE_A(1, 0, 0);
  STAGE_B(0, 1, 1); STAGE_B(1, 1, 1);

  for (int u = 0; u < 15; ++u) {
    const int buf = u & 1, nbuf = buf ^ 1;
    // phi0: stage A0(u+1); certify K-tile u (vmcnt(6): 3 newer HT in flight).
    STAGE_A(0, u + 1, nbuf);
    WAIT_VM6();
    BARRIER();
    LDB(0, buf); LDB(1, buf); LDA(0, 0, buf);    // 12 ds_read_b128
    WAIT_LGKM0();
    __builtin_amdgcn_s_setprio(1); MFMA16(0, 0); __builtin_amdgcn_s_setprio(0);
    BARRIER();
    // phi1
    LDA(0, 1, buf);
    STAGE_A(1, u + 1, nbuf);
    COMPUTE(0, 1);
    // phi2
    LDA(1, 0, buf);
    if (u < 14) STAGE_B(0, u + 2, buf);
    COMPUTE(1, 0);
    // phi3
    LDA(1, 1, buf);
    if (u < 14) STAGE_B(1, u + 2, buf);
    COMPUTE(1, 1);
  }
  {  // u = 15 (buf 1): no staging left; natural drain.
    WAIT_VM0();
    BARRIER();
    LDB(0, 1); LDB(1, 1); LDA(0, 0, 1);
    WAIT_LGKM0();
    __builtin_amdgcn_s_setprio(1); MFMA16(0, 0); __builtin_amdgcn_s_setprio(0);
    BARRIER();
    LDA(0, 1, 1); COMPUTE(0, 1);
    LDA(1, 0, 1); COMPUTE(1, 0);
    LDA(1, 1, 1); COMPUTE(1, 1);
  }

  // Epilogue. C/D layout: col = lane&15, row = (lane>>4)*4 + j.
#pragma unroll
  for (int m = 0; m < 8; ++m)
#pragma unroll
    for (int n = 0; n < 4; ++n) {
      const int gn = n0 + wn * 64 + n * 16 + l15;
      const float bia = bias[gn];
#pragma unroll
      for (int j = 0; j < 4; ++j) {
        const int gm = m0 + wm * 128 + m * 16 + lhi * 4 + j;
        if (gm < M_REAL) C[(size_t)gm * D_DIM + gn] = acc[m][n][j] + bia;
      }
    }
#undef STAGE_A
#undef STAGE_B
#undef LDA
#undef LDB
#undef MFMA16
#undef COMPUTE
}

// ---------------------------------------------------------------------------
// Small GEMM for Wfused = Wo @ Wv (bf16 out): m97-style 128x128 tile, BK=64.
// ---------------------------------------------------------------------------
__global__ __launch_bounds__(256) void gemm_bt_kernel(
    const ushort* __restrict__ A, const ushort* __restrict__ Bm,
    ushort* __restrict__ Cb, int K, int N)
{
  __shared__ ushort As[128][64];   // 16 KB
  __shared__ ushort Bs[128][64];   // 16 KB
  const int tid  = threadIdx.x;
  const int wave = tid >> 6;
  const int lane = tid & 63;
  const int wm = wave >> 1, wn = wave & 1;
  const int n0 = blockIdx.x * 128, m0 = blockIdx.y * 128;
  const int l15 = lane & 15, lhi = lane >> 4;

  floatx4 acc[4][4] = {};

  const int srow = tid >> 3;
  const int sk8  = (tid & 7) * 8;
  const ushort* Ab = A  + (size_t)(m0 + srow) * K + sk8;
  const ushort* Bb = Bm + (size_t)(n0 + srow) * K + sk8;

  for (int k0 = 0; k0 < K; k0 += 64) {
#pragma unroll
    for (int q = 0; q < 4; ++q)
      __builtin_amdgcn_global_load_lds((gptr_t)(Ab + k0 + (size_t)q * 32 * K),
          (lptr_t)((char*)&As[0][0] + (q * 256 + wave * 64) * 16), 16, 0, 0);
#pragma unroll
    for (int q = 0; q < 4; ++q)
      __builtin_amdgcn_global_load_lds((gptr_t)(Bb + k0 + (size_t)q * 32 * K),
          (lptr_t)((char*)&Bs[0][0] + (q * 256 + wave * 64) * 16), 16, 0, 0);
    __syncthreads();

#pragma unroll
    for (int kk = 0; kk < 2; ++kk) {
      short8 af[4], bfrg[4];
#pragma unroll
      for (int i = 0; i < 4; ++i) {
        af[i]   = *(const short8*)(&As[wm * 64 + i * 16 + l15][kk * 32 + lhi * 8]);
        bfrg[i] = *(const short8*)(&Bs[wn * 64 + i * 16 + l15][kk * 32 + lhi * 8]);
      }
#pragma unroll
      for (int mi = 0; mi < 4; ++mi)
#pragma unroll
        for (int ni = 0; ni < 4; ++ni)
          acc[mi][ni] = __builtin_amdgcn_mfma_f32_16x16x32_bf16(
              af[mi], bfrg[ni], acc[mi][ni], 0, 0, 0);
    }
    __syncthreads();
  }

#pragma unroll
  for (int mi = 0; mi < 4; ++mi)
#pragma unroll
    for (int ni = 0; ni < 4; ++ni) {
      const int gn = n0 + wn * 64 + ni * 16 + l15;
#pragma unroll
      for (int j = 0; j < 4; ++j) {
        const int gm = m0 + wm * 64 + mi * 16 + lhi * 4 + j;
        Cb[(size_t)gm * N + gn] = f2bf(acc[mi][ni][j]);
      }
    }
}

// ---------------------------------------------------------------------------
// Depthwise temporal conv -> s_bf16 [M_REAL][1024].
// s[b,t,:] = sum_{i=0}^{31} w[i] * x[b, t-32+i, :]   (x[neg] = 0), t in [0,4096].
// Stable descending recurrence: s[t-1] = r*s[t] + w0*x[t-33] - (w31*r)*x[t-1].
// TCH=32 t-steps per block -> 1032 blocks (~4/CU) so TLP hides latency.
// ---------------------------------------------------------------------------
#define TCH 32
__global__ __launch_bounds__(256) void conv_kernel(
    const float* __restrict__ x, const float* __restrict__ dw,
    ushort* __restrict__ S)
{
  const int b  = blockIdx.y;
  const int d4 = threadIdx.x;               // 0..255 (float4 columns)
  const int t0 = blockIdx.x * TCH;
  const int t_hi = min(t0 + TCH - 1, T_DIM);   // T_DIM = last valid t (4096)

  float w[32];
#pragma unroll
  for (int i = 0; i < 32; ++i) w[i] = dw[i];
  const float r    = w[1] / w[0];
  const float w0   = w[0];
  const float cr32 = w[31] * r;             // C * r^32

  const float4* xb = (const float4*)(x + (size_t)b * T_DIM * D_DIM) + d4;

  float sx = 0.f, sy = 0.f, sz = 0.f, swv = 0.f;
#pragma unroll
  for (int i = 0; i < 32; ++i) {
    const int idx = t_hi - 32 + i;
    if (idx >= 0) {
      float4 v = xb[(size_t)idx * 256];
      sx += w[i] * v.x; sy += w[i] * v.y; sz += w[i] * v.z; swv += w[i] * v.w;
    }
  }
  {
    ushort4 o = make_ushort4(f2bf(sx), f2bf(sy), f2bf(sz), f2bf(swv));
    *(ushort4*)(S + (size_t)(b * (T_DIM + 1) + t_hi) * D_DIM + d4 * 4) = o;
  }
  for (int t = t_hi; t > t0; --t) {
    float ax = 0.f, ay = 0.f, az = 0.f, aw = 0.f;
    const int ia = t - 33;
    if (ia >= 0) {
      float4 v = xb[(size_t)ia * 256];
      ax = v.x; ay = v.y; az = v.z; aw = v.w;
    }
    const float4 vc = xb[(size_t)(t - 1) * 256];
    sx  = r * sx  + w0 * ax - cr32 * vc.x;
    sy  = r * sy  + w0 * ay - cr32 * vc.y;
    sz  = r * sz  + w0 * az - cr32 * vc.z;
    swv = r * swv + w0 * aw - cr32 * vc.w;
    ushort4 o = make_ushort4(f2bf(sx), f2bf(sy), f2bf(sz), f2bf(swv));
    *(ushort4*)(S + (size_t)(b * (T_DIM + 1) + (t - 1)) * D_DIM + d4 * 4) = o;
  }
}

// Wo fp32 -> bf16 straight copy.
__global__ void convert_wo_kernel(const float* __restrict__ Wo, ushort* __restrict__ WoB) {
  const int i = blockIdx.x * 256 + threadIdx.x;      // float4 index
  const float4 v = ((const float4*)Wo)[i];
  ushort4 o = make_ushort4(f2bf(v.x), f2bf(v.y), f2bf(v.z), f2bf(v.w));
  *(ushort4*)(WoB + (size_t)i * 4) = o;
}

// Wv fp32 -> WvT bf16 (transpose via LDS 32x32 tile).
__global__ void transpose_wv_kernel(const float* __restrict__ Wv, ushort* __restrict__ WvT) {
  __shared__ float tile[32][33];
  const int tx = threadIdx.x;   // 0..31
  const int ty = threadIdx.y;   // 0..7
  const int c0 = blockIdx.x * 32;
  const int r0 = blockIdx.y * 32;
#pragma unroll
  for (int j = 0; j < 4; ++j)
    tile[ty + j * 8][tx] = Wv[(size_t)(r0 + ty + j * 8) * D_DIM + c0 + tx];
  __syncthreads();
#pragma unroll
  for (int j = 0; j < 4; ++j)
    WvT[(size_t)(c0 + ty + j * 8) * D_DIM + r0 + tx] = f2bf(tile[tx][ty + j * 8]);
}

// cvec[j] = sum(dw) * dot(Wo[j,:], bv) + bo[j].  One wave per j.
__global__ void bias_kernel(const float* __restrict__ Wo, const float* __restrict__ bv,
                            const float* __restrict__ bo, const float* __restrict__ dw,
                            float* __restrict__ cvec) {
  const int j    = blockIdx.x * 4 + (threadIdx.x >> 6);
  const int lane = threadIdx.x & 63;
  float sumw = 0.f;
#pragma unroll
  for (int i = 0; i < 32; ++i) sumw += dw[i];
  float s = 0.f;
  for (int k = lane; k < D_DIM; k += 64) s += Wo[(size_t)j * D_DIM + k] * bv[k];
#pragma unroll
  for (int off = 32; off; off >>= 1) s += __shfl_xor(s, off, 64);
  if (lane == 0) cvec[j] = sumw * s + bo[j];
}

// ---------------------------------------------------------------------------
extern "C" void kernel_launch(void* const* d_in, const int* in_sizes, int n_in,
                              void* d_out, int out_size, void* d_ws, size_t ws_size,
                              hipStream_t stream) {
  const float* x  = (const float*)d_in[0];
  const float* Wv = (const float*)d_in[1];
  const float* bv = (const float*)d_in[2];
  const float* Wo = (const float*)d_in[3];
  const float* bo = (const float*)d_in[4];
  const float* dw = (const float*)d_in[5];
  float* out = (float*)d_out;

  // Workspace layout (~73.4 MB total).
  char* ws = (char*)d_ws;
  ushort* S      = (ushort*)ws;                                  // M_REAL*1024 bf16
  ushort* WoB    = (ushort*)(ws + (size_t)M_REAL * D_DIM * 2);   // 1024^2 bf16
  ushort* WvT    = WoB + (size_t)D_DIM * D_DIM;                  // 1024^2 bf16
  ushort* Wfused = WvT + (size_t)D_DIM * D_DIM;                  // 1024^2 bf16
  float*  cvec   = (float*)(Wfused + (size_t)D_DIM * D_DIM);     // 1024 fp32

  // 1) Weight prep (all tiny).
  convert_wo_kernel<<<dim3(D_DIM * D_DIM / 1024), dim3(256), 0, stream>>>(Wo, WoB);
  transpose_wv_kernel<<<dim3(32, 32), dim3(32, 8), 0, stream>>>(Wv, WvT);
  bias_kernel<<<dim3(256), dim3(256), 0, stream>>>(Wo, bv, bo, dw, cvec);

  // 2) Wfused[j,k] = sum_p Wo[j,p] * Wv[p,k]  (row-major bf16).
  gemm_bt_kernel<<<dim3(8, 8), dim3(256), 0, stream>>>(
      WoB, WvT, Wfused, D_DIM, D_DIM);

  // 3) Temporal conv -> s bf16.
  conv_kernel<<<dim3((T_DIM / TCH) + 1, B_DIM), dim3(256), 0, stream>>>(x, dw, S);

  // 4) out = s @ Wfused^T + cvec  (256^2, 8-phase counted-vmcnt, XCD-swizzled).
  gemm256_kernel<<<dim3(NWG), dim3(512), 0, stream>>>(S, Wfused, out, cvec);
}

// Round 5
// 192.858 us; speedup vs baseline: 1.3254x; 1.2170x over previous
//
#include <hip/hip_runtime.h>
#include <stdint.h>

// Problem constants (from reference): B=8, T=4096, D=1024, H=32.
#define D_DIM 1024
#define T_DIM 4096
#define B_DIM 8
#define M_REAL (B_DIM * (T_DIM + 1))   // 32776 output rows
#define M_MAIN 32768                    // 128 m-panels x 256 (tail 8 rows via GEMV)
#define NWG 512                         // 128 x 4 blocks, 1/CU, exactly 2 rounds

typedef short short8 __attribute__((ext_vector_type(8)));   // 8 bf16 (4 VGPRs)
typedef float floatx4 __attribute__((ext_vector_type(4)));  // 4 fp32 acc

typedef const __attribute__((address_space(1))) void* gptr_t;
typedef __attribute__((address_space(3))) void* lptr_t;

__device__ __forceinline__ ushort f2bf(float f) {
  union { float f; uint32_t u; } v; v.f = f;
  uint32_t r = v.u + 0x7FFF + ((v.u >> 16) & 1);  // RNE
  return (ushort)(r >> 16);
}
__device__ __forceinline__ float bf2f(ushort b) {
  union { uint32_t u; float f; } v; v.u = ((uint32_t)b) << 16; return v.f;
}

#define BARRIER()  asm volatile("s_barrier" ::: "memory")
#define WAIT_VM6() asm volatile("s_waitcnt vmcnt(6)" ::: "memory")
#define WAIT_VM0() asm volatile("s_waitcnt vmcnt(0)" ::: "memory")
// rule #18: sched_barrier(0) after lgkmcnt so MFMA can't hoist above the wait.
#define WAIT_LGKM0() do { asm volatile("s_waitcnt lgkmcnt(0)" ::: "memory"); \
                          __builtin_amdgcn_sched_barrier(0); } while (0)

// ---------------------------------------------------------------------------
// Main GEMM: C[m,n] = sum_k A[m,k]*B[n,k] + bias[n].  A,B bf16 row-major.
// 256x256 tile, BK=64, 8 waves (2M x 4N), per-wave 128x64 output.
// 8-phase schedule (T2+T3+T4+T5): 128KB LDS = 2 dbuf x {A,B} x 2 halves of
// [128 rows][64 cols] bf16 (16KB each).
// Bank swizzle (3-bit, balance-verified): read phys = o ^ ((row&7)<<4) so the
// 16 rows of a frag-group spread over all 8 bank-groups (8 words/bank).
// global_load_lds writes LINEAR dest; source pre-swizzled per involution
// chunk_log = chunk_phys ^ ((chunk_phys>>3)&7)  (row bits preserved).
// Stage order per K-tile u: B0,B1,A0,A1; issued 6 half-tiles ahead; vmcnt(6)
// once per K-tile at phi0 (3 newer half-tiles = 6 loads stay in flight).
// ---------------------------------------------------------------------------
__global__ __launch_bounds__(512, 2) void gemm256_kernel(
    const ushort* __restrict__ A, const ushort* __restrict__ Bm,
    float* __restrict__ C, const float* __restrict__ bias)
{
  __shared__ char smem[131072];   // [A|B][buf][half] 16KB slots; B at +65536
  const int tid  = threadIdx.x;
  const int wave = tid >> 6;
  const int lane = tid & 63;
  const int wm = wave >> 2, wn = wave & 3;     // 2 x 4 wave grid
  const int l15 = lane & 15, lhi = lane >> 4;
  const int rsw = (l15 & 7) << 4;              // read-side bank swizzle bits

  // m204 bijective XCD swizzle, nwg=512: q=64, r=0.
  const int bid = blockIdx.x;
  const int wg  = (bid & 7) * 64 + (bid >> 3);
  const int n0 = (wg & 3) * 256;
  const int m0 = (wg >> 2) * 256;              // <= 32512; max row 32767 < M_REAL

  // Staging source map. Half-tile = [128 rows][64 cols] bf16 = 1024 16B-chunks.
  // Thread stages phys chunks d = tid (j=0) and d = 512+tid (j=1) linearly;
  // fetches LOGICAL chunk d ^ ((d>>3)&7): row = d>>3 unchanged, k permuted.
  const int rowc = tid >> 3;                                   // 0..63 (+64 j=1)
  const int ksw  = ((tid ^ ((tid >> 3) & 7)) & 7) * 8;         // swizzled k-elems

  const ushort* Asrc[2][2]; const ushort* Bsrc[2][2];   // [half][j]
#pragma unroll
  for (int h = 0; h < 2; ++h)
#pragma unroll
    for (int j = 0; j < 2; ++j) {
      Asrc[h][j] = A  + (size_t)(m0 + h * 128 + rowc + j * 64) * D_DIM + ksw;
      Bsrc[h][j] = Bm + (size_t)(n0 + h * 128 + rowc + j * 64) * D_DIM + ksw;
    }

#define STAGE_A(H, U, BUF) do { \
  __builtin_amdgcn_global_load_lds((gptr_t)(Asrc[H][0] + (U) * 64), \
      (lptr_t)(smem + ((BUF) * 2 + (H)) * 16384 + wave * 1024), 16, 0, 0); \
  __builtin_amdgcn_global_load_lds((gptr_t)(Asrc[H][1] + (U) * 64), \
      (lptr_t)(smem + ((BUF) * 2 + (H)) * 16384 + 8192 + wave * 1024), 16, 0, 0); \
} while (0)
#define STAGE_B(H, U, BUF) do { \
  __builtin_amdgcn_global_load_lds((gptr_t)(Bsrc[H][0] + (U) * 64), \
      (lptr_t)(smem + 65536 + ((BUF) * 2 + (H)) * 16384 + wave * 1024), 16, 0, 0); \
  __builtin_amdgcn_global_load_lds((gptr_t)(Bsrc[H][1] + (U) * 64), \
      (lptr_t)(smem + 65536 + ((BUF) * 2 + (H)) * 16384 + 8192 + wave * 1024), 16, 0, 0); \
} while (0)

  short8 a[4];        // current-phase A frags
  short8 bfr[2][4];   // B frags, both k-slices, live across the K-tile
  floatx4 acc[8][4] = {};

// Swizzled ds_read: logical o = row*128 + KK*64 + lhi*16; row&7 == l15&7.
#define LDA(MH, KK, BUF) do { \
  const char* _ab = smem + ((BUF) * 2 + wm) * 16384; \
  _Pragma("unroll") \
  for (int mp = 0; mp < 4; ++mp) { \
    int o = (((MH) * 64 + mp * 16 + l15) * 128 + (KK) * 64 + lhi * 16) ^ rsw; \
    a[mp] = *(const short8*)(_ab + o); \
  } } while (0)
#define LDB(KK, BUF) do { \
  const char* _bb = smem + 65536 + ((BUF) * 2 + (wn >> 1)) * 16384; \
  _Pragma("unroll") \
  for (int n = 0; n < 4; ++n) { \
    int o = (((wn & 1) * 64 + n * 16 + l15) * 128 + (KK) * 64 + lhi * 16) ^ rsw; \
    bfr[KK][n] = *(const short8*)(_bb + o); \
  } } while (0)

#define MFMA16(MH, KK) do { \
  _Pragma("unroll") \
  for (int mp = 0; mp < 4; ++mp) \
    _Pragma("unroll") \
    for (int n = 0; n < 4; ++n) \
      acc[(MH) * 4 + mp][n] = __builtin_amdgcn_mfma_f32_16x16x32_bf16( \
          a[mp], bfr[KK][n], acc[(MH) * 4 + mp][n], 0, 0, 0); \
} while (0)

#define COMPUTE(MH, KK) do { BARRIER(); WAIT_LGKM0(); \
  __builtin_amdgcn_s_setprio(1); MFMA16(MH, KK); __builtin_amdgcn_s_setprio(0); \
  BARRIER(); } while (0)

  // Prologue: stage sigma = 0..5 in order (K-tile0 B0,B1,A0,A1; K-tile1 B0,B1).
  STAGE_B(0, 0, 0); STAGE_B(1, 0, 0); STAGE_A(0, 0, 0); STAGE_A(1, 0, 0);
  STAGE_B(0, 1, 1); STAGE_B(1, 1, 1);

  for (int u = 0; u < 15; ++u) {
    const int buf = u & 1, nbuf = buf ^ 1;
    // phi0: stage A0(u+1); certify K-tile u (vmcnt(6): 3 newer HT in flight).
    STAGE_A(0, u + 1, nbuf);
    WAIT_VM6();
    BARRIER();
    LDB(0, buf); LDB(1, buf); LDA(0, 0, buf);    // 12 ds_read_b128
    WAIT_LGKM0();
    __builtin_amdgcn_s_setprio(1); MFMA16(0, 0); __builtin_amdgcn_s_setprio(0);
    BARRIER();
    // phi1
    LDA(0, 1, buf);
    STAGE_A(1, u + 1, nbuf);
    COMPUTE(0, 1);
    // phi2
    LDA(1, 0, buf);
    if (u < 14) STAGE_B(0, u + 2, buf);
    COMPUTE(1, 0);
    // phi3
    LDA(1, 1, buf);
    if (u < 14) STAGE_B(1, u + 2, buf);
    COMPUTE(1, 1);
  }
  {  // u = 15 (buf 1): no staging left; natural drain.
    WAIT_VM0();
    BARRIER();
    LDB(0, 1); LDB(1, 1); LDA(0, 0, 1);
    WAIT_LGKM0();
    __builtin_amdgcn_s_setprio(1); MFMA16(0, 0); __builtin_amdgcn_s_setprio(0);
    BARRIER();
    LDA(0, 1, 1); COMPUTE(0, 1);
    LDA(1, 0, 1); COMPUTE(1, 0);
    LDA(1, 1, 1); COMPUTE(1, 1);
  }

  // Epilogue. C/D layout: col = lane&15, row = (lane>>4)*4 + j. No m-guard:
  // max gm = 32512 + 128 + 48 + 12 + 3 = 32767 < M_REAL.
#pragma unroll
  for (int m = 0; m < 8; ++m)
#pragma unroll
    for (int n = 0; n < 4; ++n) {
      const int gn = n0 + wn * 64 + n * 16 + l15;
      const float bia = bias[gn];
#pragma unroll
      for (int j = 0; j < 4; ++j) {
        const int gm = m0 + wm * 128 + m * 16 + lhi * 4 + j;
        C[(size_t)gm * D_DIM + gn] = acc[m][n][j] + bia;
      }
    }
#undef STAGE_A
#undef STAGE_B
#undef LDA
#undef LDB
#undef MFMA16
#undef COMPUTE
}

// ---------------------------------------------------------------------------
// Tail GEMV: out[r,c] for r in [32768, 32776), all 1024 cols.
// 256 blocks x 4 waves; wave = one col, lanes split K; shuffle-reduce.
// ---------------------------------------------------------------------------
__global__ __launch_bounds__(256) void tail_gemv_kernel(
    const ushort* __restrict__ S, const ushort* __restrict__ Wf,
    const float* __restrict__ cvec, float* __restrict__ out)
{
  const int wavei = threadIdx.x >> 6, lane = threadIdx.x & 63;
  const int c = blockIdx.x * 4 + wavei;
  float acc[8] = {};
  for (int i = 0; i < 16; ++i) {
    const int k = i * 64 + lane;
    const float wv = bf2f(Wf[(size_t)c * D_DIM + k]);
#pragma unroll
    for (int r = 0; r < 8; ++r)
      acc[r] += wv * bf2f(S[(size_t)(M_MAIN + r) * D_DIM + k]);
  }
#pragma unroll
  for (int r = 0; r < 8; ++r) {
#pragma unroll
    for (int off = 32; off; off >>= 1) acc[r] += __shfl_xor(acc[r], off, 64);
  }
  if (lane == 0) {
    const float bia = cvec[c];
#pragma unroll
    for (int r = 0; r < 8; ++r)
      out[(size_t)(M_MAIN + r) * D_DIM + c] = acc[r] + bia;
  }
}

// ---------------------------------------------------------------------------
// Small GEMM for Wfused = Wo @ Wv (bf16 out): m97-style 128x128 tile, BK=64.
// ---------------------------------------------------------------------------
__global__ __launch_bounds__(256) void gemm_bt_kernel(
    const ushort* __restrict__ A, const ushort* __restrict__ Bm,
    ushort* __restrict__ Cb, int K, int N)
{
  __shared__ ushort As[128][64];   // 16 KB
  __shared__ ushort Bs[128][64];   // 16 KB
  const int tid  = threadIdx.x;
  const int wave = tid >> 6;
  const int lane = tid & 63;
  const int wm = wave >> 1, wn = wave & 1;
  const int n0 = blockIdx.x * 128, m0 = blockIdx.y * 128;
  const int l15 = lane & 15, lhi = lane >> 4;

  floatx4 acc[4][4] = {};

  const int srow = tid >> 3;
  const int sk8  = (tid & 7) * 8;
  const ushort* Ab = A  + (size_t)(m0 + srow) * K + sk8;
  const ushort* Bb = Bm + (size_t)(n0 + srow) * K + sk8;

  for (int k0 = 0; k0 < K; k0 += 64) {
#pragma unroll
    for (int q = 0; q < 4; ++q)
      __builtin_amdgcn_global_load_lds((gptr_t)(Ab + k0 + (size_t)q * 32 * K),
          (lptr_t)((char*)&As[0][0] + (q * 256 + wave * 64) * 16), 16, 0, 0);
#pragma unroll
    for (int q = 0; q < 4; ++q)
      __builtin_amdgcn_global_load_lds((gptr_t)(Bb + k0 + (size_t)q * 32 * K),
          (lptr_t)((char*)&Bs[0][0] + (q * 256 + wave * 64) * 16), 16, 0, 0);
    __syncthreads();

#pragma unroll
    for (int kk = 0; kk < 2; ++kk) {
      short8 af[4], bfrg[4];
#pragma unroll
      for (int i = 0; i < 4; ++i) {
        af[i]   = *(const short8*)(&As[wm * 64 + i * 16 + l15][kk * 32 + lhi * 8]);
        bfrg[i] = *(const short8*)(&Bs[wn * 64 + i * 16 + l15][kk * 32 + lhi * 8]);
      }
#pragma unroll
      for (int mi = 0; mi < 4; ++mi)
#pragma unroll
        for (int ni = 0; ni < 4; ++ni)
          acc[mi][ni] = __builtin_amdgcn_mfma_f32_16x16x32_bf16(
              af[mi], bfrg[ni], acc[mi][ni], 0, 0, 0);
    }
    __syncthreads();
  }

#pragma unroll
  for (int mi = 0; mi < 4; ++mi)
#pragma unroll
    for (int ni = 0; ni < 4; ++ni) {
      const int gn = n0 + wn * 64 + ni * 16 + l15;
#pragma unroll
      for (int j = 0; j < 4; ++j) {
        const int gm = m0 + wm * 64 + mi * 16 + lhi * 4 + j;
        Cb[(size_t)gm * N + gn] = f2bf(acc[mi][ni][j]);
      }
    }
}

// ---------------------------------------------------------------------------
// Depthwise temporal conv -> s_bf16 [M_REAL][1024].
// s[b,t,:] = sum_{i=0}^{31} w[i] * x[b, t-32+i, :]   (x[neg] = 0), t in [0,4096].
// Stable descending recurrence: s[t-1] = r*s[t] + w0*x[t-33] - (w31*r)*x[t-1].
// TCH=32 t-steps per block -> 1032 blocks (~4/CU) so TLP hides latency.
// ---------------------------------------------------------------------------
#define TCH 32
__global__ __launch_bounds__(256) void conv_kernel(
    const float* __restrict__ x, const float* __restrict__ dw,
    ushort* __restrict__ S)
{
  const int b  = blockIdx.y;
  const int d4 = threadIdx.x;               // 0..255 (float4 columns)
  const int t0 = blockIdx.x * TCH;
  const int t_hi = min(t0 + TCH - 1, T_DIM);   // T_DIM = last valid t (4096)

  float w[32];
#pragma unroll
  for (int i = 0; i < 32; ++i) w[i] = dw[i];
  const float r    = w[1] / w[0];
  const float w0   = w[0];
  const float cr32 = w[31] * r;             // C * r^32

  const float4* xb = (const float4*)(x + (size_t)b * T_DIM * D_DIM) + d4;

  float sx = 0.f, sy = 0.f, sz = 0.f, swv = 0.f;
#pragma unroll
  for (int i = 0; i < 32; ++i) {
    const int idx = t_hi - 32 + i;
    if (idx >= 0) {
      float4 v = xb[(size_t)idx * 256];
      sx += w[i] * v.x; sy += w[i] * v.y; sz += w[i] * v.z; swv += w[i] * v.w;
    }
  }
  {
    ushort4 o = make_ushort4(f2bf(sx), f2bf(sy), f2bf(sz), f2bf(swv));
    *(ushort4*)(S + (size_t)(b * (T_DIM + 1) + t_hi) * D_DIM + d4 * 4) = o;
  }
  for (int t = t_hi; t > t0; --t) {
    float ax = 0.f, ay = 0.f, az = 0.f, aw = 0.f;
    const int ia = t - 33;
    if (ia >= 0) {
      float4 v = xb[(size_t)ia * 256];
      ax = v.x; ay = v.y; az = v.z; aw = v.w;
    }
    const float4 vc = xb[(size_t)(t - 1) * 256];
    sx  = r * sx  + w0 * ax - cr32 * vc.x;
    sy  = r * sy  + w0 * ay - cr32 * vc.y;
    sz  = r * sz  + w0 * az - cr32 * vc.z;
    swv = r * swv + w0 * aw - cr32 * vc.w;
    ushort4 o = make_ushort4(f2bf(sx), f2bf(sy), f2bf(sz), f2bf(swv));
    *(ushort4*)(S + (size_t)(b * (T_DIM + 1) + (t - 1)) * D_DIM + d4 * 4) = o;
  }
}

// Wo fp32 -> bf16 straight copy.
__global__ void convert_wo_kernel(const float* __restrict__ Wo, ushort* __restrict__ WoB) {
  const int i = blockIdx.x * 256 + threadIdx.x;      // float4 index
  const float4 v = ((const float4*)Wo)[i];
  ushort4 o = make_ushort4(f2bf(v.x), f2bf(v.y), f2bf(v.z), f2bf(v.w));
  *(ushort4*)(WoB + (size_t)i * 4) = o;
}

// Wv fp32 -> WvT bf16 (transpose via LDS 32x32 tile).
__global__ void transpose_wv_kernel(const float* __restrict__ Wv, ushort* __restrict__ WvT) {
  __shared__ float tile[32][33];
  const int tx = threadIdx.x;   // 0..31
  const int ty = threadIdx.y;   // 0..7
  const int c0 = blockIdx.x * 32;
  const int r0 = blockIdx.y * 32;
#pragma unroll
  for (int j = 0; j < 4; ++j)
    tile[ty + j * 8][tx] = Wv[(size_t)(r0 + ty + j * 8) * D_DIM + c0 + tx];
  __syncthreads();
#pragma unroll
  for (int j = 0; j < 4; ++j)
    WvT[(size_t)(c0 + ty + j * 8) * D_DIM + r0 + tx] = f2bf(tile[tx][ty + j * 8]);
}

// cvec[j] = sum(dw) * dot(Wo[j,:], bv) + bo[j].  One wave per j.
__global__ void bias_kernel(const float* __restrict__ Wo, const float* __restrict__ bv,
                            const float* __restrict__ bo, const float* __restrict__ dw,
                            float* __restrict__ cvec) {
  const int j    = blockIdx.x * 4 + (threadIdx.x >> 6);
  const int lane = threadIdx.x & 63;
  float sumw = 0.f;
#pragma unroll
  for (int i = 0; i < 32; ++i) sumw += dw[i];
  float s = 0.f;
  for (int k = lane; k < D_DIM; k += 64) s += Wo[(size_t)j * D_DIM + k] * bv[k];
#pragma unroll
  for (int off = 32; off; off >>= 1) s += __shfl_xor(s, off, 64);
  if (lane == 0) cvec[j] = sumw * s + bo[j];
}

// ---------------------------------------------------------------------------
extern "C" void kernel_launch(void* const* d_in, const int* in_sizes, int n_in,
                              void* d_out, int out_size, void* d_ws, size_t ws_size,
                              hipStream_t stream) {
  const float* x  = (const float*)d_in[0];
  const float* Wv = (const float*)d_in[1];
  const float* bv = (const float*)d_in[2];
  const float* Wo = (const float*)d_in[3];
  const float* bo = (const float*)d_in[4];
  const float* dw = (const float*)d_in[5];
  float* out = (float*)d_out;

  // Workspace layout (~73.4 MB total).
  char* ws = (char*)d_ws;
  ushort* S      = (ushort*)ws;                                  // M_REAL*1024 bf16
  ushort* WoB    = (ushort*)(ws + (size_t)M_REAL * D_DIM * 2);   // 1024^2 bf16
  ushort* WvT    = WoB + (size_t)D_DIM * D_DIM;                  // 1024^2 bf16
  ushort* Wfused = WvT + (size_t)D_DIM * D_DIM;                  // 1024^2 bf16
  float*  cvec   = (float*)(Wfused + (size_t)D_DIM * D_DIM);     // 1024 fp32

  // 1) Weight prep (all tiny).
  convert_wo_kernel<<<dim3(D_DIM * D_DIM / 1024), dim3(256), 0, stream>>>(Wo, WoB);
  transpose_wv_kernel<<<dim3(32, 32), dim3(32, 8), 0, stream>>>(Wv, WvT);
  bias_kernel<<<dim3(256), dim3(256), 0, stream>>>(Wo, bv, bo, dw, cvec);

  // 2) Wfused[j,k] = sum_p Wo[j,p] * Wv[p,k]  (row-major bf16).
  gemm_bt_kernel<<<dim3(8, 8), dim3(256), 0, stream>>>(
      WoB, WvT, Wfused, D_DIM, D_DIM);

  // 3) Temporal conv -> s bf16.
  conv_kernel<<<dim3((T_DIM / TCH) + 1, B_DIM), dim3(256), 0, stream>>>(x, dw, S);

  // 4) out = s @ Wfused^T + cvec  (256^2, 8-phase counted-vmcnt, XCD-swizzled,
  //    exactly 2 rounds of 256 blocks) + 8-row GEMV tail.
  gemm256_kernel<<<dim3(NWG), dim3(512), 0, stream>>>(S, Wfused, out, cvec);
  tail_gemv_kernel<<<dim3(256), dim3(256), 0, stream>>>(S, Wfused, cvec, out);
}

// Round 6
// 166.412 us; speedup vs baseline: 1.5360x; 1.1589x over previous
//
#include <hip/hip_runtime.h>
#include <stdint.h>

// Problem constants (from reference): B=8, T=4096, D=1024, H=32.
#define D_DIM 1024
#define T_DIM 4096
#define B_DIM 8
#define M_REAL (B_DIM * (T_DIM + 1))   // 32776 output rows
#define M_MAIN 32768                    // 128 m-panels x 256 (tail 8 rows via GEMV)
#define NWG 512                         // 128 x 4 blocks, 1/CU, exactly 2 rounds

typedef short short8 __attribute__((ext_vector_type(8)));   // 8 bf16 (4 VGPRs)
typedef float floatx4 __attribute__((ext_vector_type(4)));  // 4 fp32 acc

typedef const __attribute__((address_space(1))) void* gptr_t;
typedef __attribute__((address_space(3))) void* lptr_t;

__device__ __forceinline__ ushort f2bf(float f) {
  union { float f; uint32_t u; } v; v.f = f;
  uint32_t r = v.u + 0x7FFF + ((v.u >> 16) & 1);  // RNE
  return (ushort)(r >> 16);
}
__device__ __forceinline__ float bf2f(ushort b) {
  union { uint32_t u; float f; } v; v.u = ((uint32_t)b) << 16; return v.f;
}

#define BARRIER()  asm volatile("s_barrier" ::: "memory")
#define WAIT_VM8() asm volatile("s_waitcnt vmcnt(8)" ::: "memory")
#define WAIT_VM0() asm volatile("s_waitcnt vmcnt(0)" ::: "memory")
// rule #18: sched_barrier(0) after lgkmcnt so MFMA can't hoist above the wait.
#define WAIT_LGKM0() do { asm volatile("s_waitcnt lgkmcnt(0)" ::: "memory"); \
                          __builtin_amdgcn_sched_barrier(0); } while (0)
#define WAIT_LGKM4() do { asm volatile("s_waitcnt lgkmcnt(4)" ::: "memory"); \
                          __builtin_amdgcn_sched_barrier(0); } while (0)
#define WAIT_LGKM8() do { asm volatile("s_waitcnt lgkmcnt(8)" ::: "memory"); \
                          __builtin_amdgcn_sched_barrier(0); } while (0)
#define SP1() __builtin_amdgcn_s_setprio(1)
#define SP0() __builtin_amdgcn_s_setprio(0)

// ---------------------------------------------------------------------------
// Main GEMM: C[m,n] = sum_k A[m,k]*B[n,k] + bias[n].  A,B bf16 row-major.
// 256x256 tile, BK=64, 8 waves (2M x 4N), per-wave 128x64 output.
// Relaxed-barrier schedule: 3 barriers + ONE counted vmcnt(8) per K-tile.
// True hazards only: (certify: staged data of tile u ready before reads),
// (mid: all waves' LDB(buf) in regs before restaging B[buf]),
// (end: all waves' LDA(buf) in regs before restaging A[buf] next tile).
// Everything else is wave-local lgkmcnt — waves free-run between barriers,
// so one wave's MFMA overlaps the other SIMD-resident wave's ds_reads.
// Stage cadence: top(u): A(u+1)->A[nbuf] (4 loads); mid(u): B(u+2)->B[buf]
// (4 loads). certify(u) needs A(u),B(u) done; newest 8 (B(u+1),A(u+1)) may
// remain in flight -> vmcnt(8), uniform for u=0..14 (prologue 12 loads).
// LDS 128KB: A slots (BUF*2+half)*16KB, B at +64KB. Bank swizzle as r5:
// read phys = o ^ ((l15&7)<<4); source pre-swizzled chunk^((chunk>>3)&7).
// ---------------------------------------------------------------------------
__global__ __launch_bounds__(512, 2) void gemm256_kernel(
    const ushort* __restrict__ A, const ushort* __restrict__ Bm,
    float* __restrict__ C, const float* __restrict__ bias)
{
  __shared__ char smem[131072];
  const int tid  = threadIdx.x;
  const int wave = tid >> 6;
  const int lane = tid & 63;
  const int wm = wave >> 2, wn = wave & 3;     // 2 x 4 wave grid
  const int l15 = lane & 15, lhi = lane >> 4;
  const int rsw = (l15 & 7) << 4;              // read-side bank swizzle bits

  // m204 bijective XCD swizzle, nwg=512: q=64, r=0.
  const int bid = blockIdx.x;
  const int wg  = (bid & 7) * 64 + (bid >> 3);
  const int n0 = (wg & 3) * 256;
  const int m0 = (wg >> 2) * 256;              // <= 32512; max row 32767 < M_REAL

  // Staging source map (linear LDS dest, pre-swizzled global source).
  const int rowc = tid >> 3;                                   // 0..63 (+64 j=1)
  const int ksw  = ((tid ^ ((tid >> 3) & 7)) & 7) * 8;         // swizzled k-elems

  const ushort* Asrc[2][2]; const ushort* Bsrc[2][2];   // [half][j]
#pragma unroll
  for (int h = 0; h < 2; ++h)
#pragma unroll
    for (int j = 0; j < 2; ++j) {
      Asrc[h][j] = A  + (size_t)(m0 + h * 128 + rowc + j * 64) * D_DIM + ksw;
      Bsrc[h][j] = Bm + (size_t)(n0 + h * 128 + rowc + j * 64) * D_DIM + ksw;
    }

#define STAGE_A(H, U, BUF) do { \
  __builtin_amdgcn_global_load_lds((gptr_t)(Asrc[H][0] + (U) * 64), \
      (lptr_t)(smem + ((BUF) * 2 + (H)) * 16384 + wave * 1024), 16, 0, 0); \
  __builtin_amdgcn_global_load_lds((gptr_t)(Asrc[H][1] + (U) * 64), \
      (lptr_t)(smem + ((BUF) * 2 + (H)) * 16384 + 8192 + wave * 1024), 16, 0, 0); \
} while (0)
#define STAGE_B(H, U, BUF) do { \
  __builtin_amdgcn_global_load_lds((gptr_t)(Bsrc[H][0] + (U) * 64), \
      (lptr_t)(smem + 65536 + ((BUF) * 2 + (H)) * 16384 + wave * 1024), 16, 0, 0); \
  __builtin_amdgcn_global_load_lds((gptr_t)(Bsrc[H][1] + (U) * 64), \
      (lptr_t)(smem + 65536 + ((BUF) * 2 + (H)) * 16384 + 8192 + wave * 1024), 16, 0, 0); \
} while (0)

  short8 a0[4], a1[4];   // A frags for k-slice 0 / 1
  short8 bfr[2][4];      // B frags, both k-slices, live across the K-tile
  floatx4 acc[8][4] = {};

#define LDA(DST, MH, KK, BUF) do { \
  const char* _ab = smem + ((BUF) * 2 + wm) * 16384; \
  _Pragma("unroll") \
  for (int mp = 0; mp < 4; ++mp) { \
    int o = (((MH) * 64 + mp * 16 + l15) * 128 + (KK) * 64 + lhi * 16) ^ rsw; \
    DST[mp] = *(const short8*)(_ab + o); \
  } } while (0)
#define LDB(KK, BUF) do { \
  const char* _bb = smem + 65536 + ((BUF) * 2 + (wn >> 1)) * 16384; \
  _Pragma("unroll") \
  for (int n = 0; n < 4; ++n) { \
    int o = (((wn & 1) * 64 + n * 16 + l15) * 128 + (KK) * 64 + lhi * 16) ^ rsw; \
    bfr[KK][n] = *(const short8*)(_bb + o); \
  } } while (0)

#define MFMA16(MH, KK, FR) do { \
  _Pragma("unroll") \
  for (int mp = 0; mp < 4; ++mp) \
    _Pragma("unroll") \
    for (int n = 0; n < 4; ++n) \
      acc[(MH) * 4 + mp][n] = __builtin_amdgcn_mfma_f32_16x16x32_bf16( \
          FR[mp], bfr[KK][n], acc[(MH) * 4 + mp][n], 0, 0, 0); \
} while (0)

  // Prologue: A(0)->A[0], B(0)->B[0], B(1)->B[1]   (12 loads).
  STAGE_A(0, 0, 0); STAGE_A(1, 0, 0);
  STAGE_B(0, 0, 0); STAGE_B(1, 0, 0);
  STAGE_B(0, 1, 1); STAGE_B(1, 1, 1);

  for (int u = 0; u < 15; ++u) {
    const int buf = u & 1, nbuf = buf ^ 1;
    STAGE_A(0, u + 1, nbuf); STAGE_A(1, u + 1, nbuf);   // A[nbuf] freed at end(u-1)
    WAIT_VM8();                                          // A(u),B(u) landed
    BARRIER();                                           // certify
    LDB(0, buf); LDA(a0, 0, 0, buf); LDB(1, buf); LDA(a1, 0, 1, buf);  // 16 reads
    WAIT_LGKM8();                     // oldest 8 = LDB0 + a0 done
    SP1(); MFMA16(0, 0, a0); SP0();
    WAIT_LGKM0();
    SP1(); MFMA16(0, 1, a1); SP0();
    BARRIER();                        // all waves' LDB in regs -> B[buf] free
    if (u < 14) { STAGE_B(0, u + 2, buf); STAGE_B(1, u + 2, buf); }
    LDA(a0, 1, 0, buf); LDA(a1, 1, 1, buf);              // 8 reads
    WAIT_LGKM4();
    SP1(); MFMA16(1, 0, a0); SP0();
    WAIT_LGKM0();
    SP1(); MFMA16(1, 1, a1); SP0();
    BARRIER();                        // all waves' LDA in regs -> A[buf] free
  }
  {  // u = 15 (buf 1): nothing left to stage; natural drain.
    WAIT_VM0();
    BARRIER();
    LDB(0, 1); LDA(a0, 0, 0, 1); LDB(1, 1); LDA(a1, 0, 1, 1);
    WAIT_LGKM8(); SP1(); MFMA16(0, 0, a0); SP0();
    WAIT_LGKM0(); SP1(); MFMA16(0, 1, a1); SP0();
    LDA(a0, 1, 0, 1); LDA(a1, 1, 1, 1);
    WAIT_LGKM4(); SP1(); MFMA16(1, 0, a0); SP0();
    WAIT_LGKM0(); SP1(); MFMA16(1, 1, a1); SP0();
  }

  // Epilogue. C/D layout: col = lane&15, row = (lane>>4)*4 + j. No m-guard:
  // max gm = 32512 + 128 + 112 + 12 + 3 = 32767 < M_REAL.
#pragma unroll
  for (int m = 0; m < 8; ++m)
#pragma unroll
    for (int n = 0; n < 4; ++n) {
      const int gn = n0 + wn * 64 + n * 16 + l15;
      const float bia = bias[gn];
#pragma unroll
      for (int j = 0; j < 4; ++j) {
        const int gm = m0 + wm * 128 + m * 16 + lhi * 4 + j;
        C[(size_t)gm * D_DIM + gn] = acc[m][n][j] + bia;
      }
    }
#undef STAGE_A
#undef STAGE_B
#undef LDA
#undef LDB
#undef MFMA16
}

// ---------------------------------------------------------------------------
// Tail GEMV: out[r,c] for r in [32768, 32776), all 1024 cols.
// ---------------------------------------------------------------------------
__global__ __launch_bounds__(256) void tail_gemv_kernel(
    const ushort* __restrict__ S, const ushort* __restrict__ Wf,
    const float* __restrict__ cvec, float* __restrict__ out)
{
  const int wavei = threadIdx.x >> 6, lane = threadIdx.x & 63;
  const int c = blockIdx.x * 4 + wavei;
  float acc[8] = {};
  for (int i = 0; i < 16; ++i) {
    const int k = i * 64 + lane;
    const float wv = bf2f(Wf[(size_t)c * D_DIM + k]);
#pragma unroll
    for (int r = 0; r < 8; ++r)
      acc[r] += wv * bf2f(S[(size_t)(M_MAIN + r) * D_DIM + k]);
  }
#pragma unroll
  for (int r = 0; r < 8; ++r) {
#pragma unroll
    for (int off = 32; off; off >>= 1) acc[r] += __shfl_xor(acc[r], off, 64);
  }
  if (lane == 0) {
    const float bia = cvec[c];
#pragma unroll
    for (int r = 0; r < 8; ++r)
      out[(size_t)(M_MAIN + r) * D_DIM + c] = acc[r] + bia;
  }
}

// ---------------------------------------------------------------------------
// Small GEMM for Wfused = Wo @ Wv (bf16 out): m97-style 128x128 tile, BK=64.
// ---------------------------------------------------------------------------
__global__ __launch_bounds__(256) void gemm_bt_kernel(
    const ushort* __restrict__ A, const ushort* __restrict__ Bm,
    ushort* __restrict__ Cb, int K, int N)
{
  __shared__ ushort As[128][64];   // 16 KB
  __shared__ ushort Bs[128][64];   // 16 KB
  const int tid  = threadIdx.x;
  const int wave = tid >> 6;
  const int lane = tid & 63;
  const int wm = wave >> 1, wn = wave & 1;
  const int n0 = blockIdx.x * 128, m0 = blockIdx.y * 128;
  const int l15 = lane & 15, lhi = lane >> 4;

  floatx4 acc[4][4] = {};

  const int srow = tid >> 3;
  const int sk8  = (tid & 7) * 8;
  const ushort* Ab = A  + (size_t)(m0 + srow) * K + sk8;
  const ushort* Bb = Bm + (size_t)(n0 + srow) * K + sk8;

  for (int k0 = 0; k0 < K; k0 += 64) {
#pragma unroll
    for (int q = 0; q < 4; ++q)
      __builtin_amdgcn_global_load_lds((gptr_t)(Ab + k0 + (size_t)q * 32 * K),
          (lptr_t)((char*)&As[0][0] + (q * 256 + wave * 64) * 16), 16, 0, 0);
#pragma unroll
    for (int q = 0; q < 4; ++q)
      __builtin_amdgcn_global_load_lds((gptr_t)(Bb + k0 + (size_t)q * 32 * K),
          (lptr_t)((char*)&Bs[0][0] + (q * 256 + wave * 64) * 16), 16, 0, 0);
    __syncthreads();

#pragma unroll
    for (int kk = 0; kk < 2; ++kk) {
      short8 af[4], bfrg[4];
#pragma unroll
      for (int i = 0; i < 4; ++i) {
        af[i]   = *(const short8*)(&As[wm * 64 + i * 16 + l15][kk * 32 + lhi * 8]);
        bfrg[i] = *(const short8*)(&Bs[wn * 64 + i * 16 + l15][kk * 32 + lhi * 8]);
      }
#pragma unroll
      for (int mi = 0; mi < 4; ++mi)
#pragma unroll
        for (int ni = 0; ni < 4; ++ni)
          acc[mi][ni] = __builtin_amdgcn_mfma_f32_16x16x32_bf16(
              af[mi], bfrg[ni], acc[mi][ni], 0, 0, 0);
    }
    __syncthreads();
  }

#pragma unroll
  for (int mi = 0; mi < 4; ++mi)
#pragma unroll
    for (int ni = 0; ni < 4; ++ni) {
      const int gn = n0 + wn * 64 + ni * 16 + l15;
#pragma unroll
      for (int j = 0; j < 4; ++j) {
        const int gm = m0 + wm * 64 + mi * 16 + lhi * 4 + j;
        Cb[(size_t)gm * N + gn] = f2bf(acc[mi][ni][j]);
      }
    }
}

// ---------------------------------------------------------------------------
// Depthwise temporal conv -> s_bf16.
// s[t] = sum_i w[i] x[t-32+i] (x[neg]=0), t in [0,4096].
// Ascending recurrence with batched 32-row register window + exact resync:
//   s[t] = (s[t-1] - w0*x[t-33]) / r + w31*x[t-1]
// Per 32-step group: 32 independent loads (cur window) batched -> MLP 32;
// resync s = sum w_i cur[i] (exact) caps amplification at (1/0.9)^32 ~ 29x
// of fp32 eps. Block = 128 outputs (t0+1..t0+128); reads (32+128) rows ->
// 1.25 reads/output. Thread owns 1 column. Grid (32, B, 4) = 1024 blocks.
// Row t=0 (all-pad window, s=0) stored by blockIdx.x==0.
// ---------------------------------------------------------------------------
#define CTCH 128
__global__ __launch_bounds__(256) void conv_kernel(
    const float* __restrict__ x, const float* __restrict__ dw,
    ushort* __restrict__ S)
{
  const int b   = blockIdx.y;
  const int col = blockIdx.z * 256 + threadIdx.x;   // 0..1023
  const int t0  = blockIdx.x * CTCH;

  float w[32];                                       // uniform -> scalar regs
#pragma unroll
  for (int i = 0; i < 32; ++i) w[i] = dw[i];
  const float rinv = w[0] / w[1];                    // 1/r
  const float w31  = w[31];
  const float c0   = -w[0] * rinv;                   // -(w0/r)

  const float* xb = x + (size_t)b * T_DIM * D_DIM + col;
  ushort*      Sb = S + (size_t)b * (T_DIM + 1) * D_DIM + col;

  float prev[32], cur[32];
  float s;
  if (blockIdx.x == 0) {
#pragma unroll
    for (int i = 0; i < 32; ++i) prev[i] = 0.f;
    s = 0.f;
    Sb[0] = f2bf(0.f);                               // row t=0
  } else {
#pragma unroll
    for (int i = 0; i < 32; ++i) prev[i] = xb[(size_t)(t0 - 32 + i) * D_DIM];
    s = 0.f;
#pragma unroll
    for (int i = 0; i < 32; ++i) s = __builtin_fmaf(w[i], prev[i], s);
  }

#pragma unroll 1
  for (int g = 0; g < 4; g += 2) {
    // group g: window cur = x[t0+g*32 .. +31] (32 independent loads, batched)
#pragma unroll
    for (int i = 0; i < 32; ++i) cur[i] = xb[(size_t)(t0 + g * 32 + i) * D_DIM];
#pragma unroll
    for (int j = 0; j < 32; ++j) {
      s = __builtin_fmaf(s, rinv, __builtin_fmaf(prev[j], c0, w31 * cur[j]));
      Sb[(size_t)(t0 + g * 32 + 1 + j) * D_DIM] = f2bf(s);
    }
    s = 0.f;                                         // exact resync from cur
#pragma unroll
    for (int i = 0; i < 32; ++i) s = __builtin_fmaf(w[i], cur[i], s);
    // group g+1: roles swap (prev <-> cur), static names (rule #20)
#pragma unroll
    for (int i = 0; i < 32; ++i) prev[i] = xb[(size_t)(t0 + (g + 1) * 32 + i) * D_DIM];
#pragma unroll
    for (int j = 0; j < 32; ++j) {
      s = __builtin_fmaf(s, rinv, __builtin_fmaf(cur[j], c0, w31 * prev[j]));
      Sb[(size_t)(t0 + (g + 1) * 32 + 1 + j) * D_DIM] = f2bf(s);
    }
    s = 0.f;
#pragma unroll
    for (int i = 0; i < 32; ++i) s = __builtin_fmaf(w[i], prev[i], s);
  }
}

// Wo fp32 -> bf16 straight copy.
__global__ void convert_wo_kernel(const float* __restrict__ Wo, ushort* __restrict__ WoB) {
  const int i = blockIdx.x * 256 + threadIdx.x;      // float4 index
  const float4 v = ((const float4*)Wo)[i];
  ushort4 o = make_ushort4(f2bf(v.x), f2bf(v.y), f2bf(v.z), f2bf(v.w));
  *(ushort4*)(WoB + (size_t)i * 4) = o;
}

// Wv fp32 -> WvT bf16 (transpose via LDS 32x32 tile).
__global__ void transpose_wv_kernel(const float* __restrict__ Wv, ushort* __restrict__ WvT) {
  __shared__ float tile[32][33];
  const int tx = threadIdx.x;   // 0..31
  const int ty = threadIdx.y;   // 0..7
  const int c0 = blockIdx.x * 32;
  const int r0 = blockIdx.y * 32;
#pragma unroll
  for (int j = 0; j < 4; ++j)
    tile[ty + j * 8][tx] = Wv[(size_t)(r0 + ty + j * 8) * D_DIM + c0 + tx];
  __syncthreads();
#pragma unroll
  for (int j = 0; j < 4; ++j)
    WvT[(size_t)(c0 + ty + j * 8) * D_DIM + r0 + tx] = f2bf(tile[tx][ty + j * 8]);
}

// cvec[j] = sum(dw) * dot(Wo[j,:], bv) + bo[j].  One wave per j.
__global__ void bias_kernel(const float* __restrict__ Wo, const float* __restrict__ bv,
                            const float* __restrict__ bo, const float* __restrict__ dw,
                            float* __restrict__ cvec) {
  const int j    = blockIdx.x * 4 + (threadIdx.x >> 6);
  const int lane = threadIdx.x & 63;
  float sumw = 0.f;
#pragma unroll
  for (int i = 0; i < 32; ++i) sumw += dw[i];
  float s = 0.f;
  for (int k = lane; k < D_DIM; k += 64) s += Wo[(size_t)j * D_DIM + k] * bv[k];
#pragma unroll
  for (int off = 32; off; off >>= 1) s += __shfl_xor(s, off, 64);
  if (lane == 0) cvec[j] = sumw * s + bo[j];
}

// ---------------------------------------------------------------------------
extern "C" void kernel_launch(void* const* d_in, const int* in_sizes, int n_in,
                              void* d_out, int out_size, void* d_ws, size_t ws_size,
                              hipStream_t stream) {
  const float* x  = (const float*)d_in[0];
  const float* Wv = (const float*)d_in[1];
  const float* bv = (const float*)d_in[2];
  const float* Wo = (const float*)d_in[3];
  const float* bo = (const float*)d_in[4];
  const float* dw = (const float*)d_in[5];
  float* out = (float*)d_out;

  // Workspace layout (~73.4 MB total).
  char* ws = (char*)d_ws;
  ushort* S      = (ushort*)ws;                                  // M_REAL*1024 bf16
  ushort* WoB    = (ushort*)(ws + (size_t)M_REAL * D_DIM * 2);   // 1024^2 bf16
  ushort* WvT    = WoB + (size_t)D_DIM * D_DIM;                  // 1024^2 bf16
  ushort* Wfused = WvT + (size_t)D_DIM * D_DIM;                  // 1024^2 bf16
  float*  cvec   = (float*)(Wfused + (size_t)D_DIM * D_DIM);     // 1024 fp32

  // 1) Weight prep (all tiny).
  convert_wo_kernel<<<dim3(D_DIM * D_DIM / 1024), dim3(256), 0, stream>>>(Wo, WoB);
  transpose_wv_kernel<<<dim3(32, 32), dim3(32, 8), 0, stream>>>(Wv, WvT);
  bias_kernel<<<dim3(256), dim3(256), 0, stream>>>(Wo, bv, bo, dw, cvec);

  // 2) Wfused[j,k] = sum_p Wo[j,p] * Wv[p,k]  (row-major bf16).
  gemm_bt_kernel<<<dim3(8, 8), dim3(256), 0, stream>>>(
      WoB, WvT, Wfused, D_DIM, D_DIM);

  // 3) Temporal conv -> s bf16 (batched-window recurrence).
  conv_kernel<<<dim3(T_DIM / CTCH, B_DIM, 4), dim3(256), 0, stream>>>(x, dw, S);

  // 4) out = s @ Wfused^T + cvec  (256^2, relaxed-barrier counted-vmcnt,
  //    XCD-swizzled, exactly 2 rounds of 256 blocks) + 8-row GEMV tail.
  gemm256_kernel<<<dim3(NWG), dim3(512), 0, stream>>>(S, Wfused, out, cvec);
  tail_gemv_kernel<<<dim3(256), dim3(256), 0, stream>>>(S, Wfused, cvec, out);
}

// Round 7
// 165.908 us; speedup vs baseline: 1.5407x; 1.0030x over previous
//
#include <hip/hip_runtime.h>
#include <stdint.h>

// Problem constants (from reference): B=8, T=4096, D=1024, H=32.
#define D_DIM 1024
#define T_DIM 4096
#define B_DIM 8
#define M_REAL (B_DIM * (T_DIM + 1))   // 32776 output rows
#define M_MAIN 32768                    // 128 m-panels x 256 (tail 8 rows via GEMV)
#define NWG 512                         // 128 x 4 blocks, 1/CU, exactly 2 rounds

typedef short short8 __attribute__((ext_vector_type(8)));   // 8 bf16 (4 VGPRs)
typedef float floatx4 __attribute__((ext_vector_type(4)));  // 4 fp32 acc

typedef const __attribute__((address_space(1))) void* gptr_t;
typedef __attribute__((address_space(3))) void* lptr_t;

__device__ __forceinline__ ushort f2bf(float f) {
  union { float f; uint32_t u; } v; v.f = f;
  uint32_t r = v.u + 0x7FFF + ((v.u >> 16) & 1);  // RNE
  return (ushort)(r >> 16);
}
__device__ __forceinline__ float bf2f(ushort b) {
  union { uint32_t u; float f; } v; v.u = ((uint32_t)b) << 16; return v.f;
}

#define BARRIER()  asm volatile("s_barrier" ::: "memory")
#define WAIT_VM8() asm volatile("s_waitcnt vmcnt(8)" ::: "memory")
#define WAIT_VM0() asm volatile("s_waitcnt vmcnt(0)" ::: "memory")
// rule #18: sched_barrier(0) after each wait so MFMA can't hoist above it.
#define WAIT_LGKM0() do { asm volatile("s_waitcnt lgkmcnt(0)" ::: "memory"); \
                          __builtin_amdgcn_sched_barrier(0); } while (0)
#define WAIT_LGKM4() do { asm volatile("s_waitcnt lgkmcnt(4)" ::: "memory"); \
                          __builtin_amdgcn_sched_barrier(0); } while (0)
#define WAIT_LGKM8() do { asm volatile("s_waitcnt lgkmcnt(8)" ::: "memory"); \
                          __builtin_amdgcn_sched_barrier(0); } while (0)
#define SP1() __builtin_amdgcn_s_setprio(1)
#define SP0() __builtin_amdgcn_s_setprio(0)

// ---------------------------------------------------------------------------
// Main GEMM: C[m,n] = sum_k A[m,k]*B[n,k] + bias[n].  A,B bf16 row-major.
// 256x256 tile, BK=64, 8 waves (2M x 4N), per-wave 128x64 output.
// Issue-early / wait-counted schedule: 2 barriers + ONE vmcnt(8) per K-tile;
// ds_reads stream in-order while earlier MFMA clusters compute (counted
// lgkmcnt retires exactly the next cluster's operands — never drain to 0
// until the last cluster). Wait-count certification (ds issue order is
// pinned by memory clobbers on every wait):
//   issue B0(4) a0(4) B1(4) a1(4)      | lgkm(8):  retires B0,a0 -> MFMA(0,0)
//   issue a2(4)   [B1,a1,a2 out =12]   | lgkm(4):  retires B1,a1 -> MFMA(0,1)
//   BARRIER (B-free) ; STAGE_B(u+2)
//   issue a3(4)   [a2,a3 out = 8]      | lgkm(4):  retires a2    -> MFMA(1,0)
//                                      | lgkm(0):  retires a3    -> MFMA(1,1)
//   BARRIER (A-free)
// vmcnt(8) at certify: in-flight = {B(u+1), A(u+1)} = 8 newest, uniformly
// for u=0..14 (prologue A0,B0,B1 = 12 loads; +A(u+1) at top).
// LDS 128KB: A slots (BUF*2+half)*16KB, B at +64KB. Bank swizzle as r5:
// read phys = o ^ ((l15&7)<<4); source pre-swizzled chunk^((chunk>>3)&7).
// ---------------------------------------------------------------------------
__global__ __launch_bounds__(512, 2) void gemm256_kernel(
    const ushort* __restrict__ A, const ushort* __restrict__ Bm,
    float* __restrict__ C, const float* __restrict__ bias)
{
  __shared__ char smem[131072];
  const int tid  = threadIdx.x;
  const int wave = tid >> 6;
  const int lane = tid & 63;
  const int wm = wave >> 2, wn = wave & 3;     // 2 x 4 wave grid
  const int l15 = lane & 15, lhi = lane >> 4;
  const int rsw = (l15 & 7) << 4;              // read-side bank swizzle bits

  // m204 bijective XCD swizzle, nwg=512: q=64, r=0.
  const int bid = blockIdx.x;
  const int wg  = (bid & 7) * 64 + (bid >> 3);
  const int n0 = (wg & 3) * 256;
  const int m0 = (wg >> 2) * 256;              // <= 32512; max row 32767 < M_REAL

  // Staging source map (linear LDS dest, pre-swizzled global source).
  const int rowc = tid >> 3;                                   // 0..63 (+64 j=1)
  const int ksw  = ((tid ^ ((tid >> 3) & 7)) & 7) * 8;         // swizzled k-elems

  const ushort* Asrc[2][2]; const ushort* Bsrc[2][2];   // [half][j]
#pragma unroll
  for (int h = 0; h < 2; ++h)
#pragma unroll
    for (int j = 0; j < 2; ++j) {
      Asrc[h][j] = A  + (size_t)(m0 + h * 128 + rowc + j * 64) * D_DIM + ksw;
      Bsrc[h][j] = Bm + (size_t)(n0 + h * 128 + rowc + j * 64) * D_DIM + ksw;
    }

#define STAGE_A(H, U, BUF) do { \
  __builtin_amdgcn_global_load_lds((gptr_t)(Asrc[H][0] + (U) * 64), \
      (lptr_t)(smem + ((BUF) * 2 + (H)) * 16384 + wave * 1024), 16, 0, 0); \
  __builtin_amdgcn_global_load_lds((gptr_t)(Asrc[H][1] + (U) * 64), \
      (lptr_t)(smem + ((BUF) * 2 + (H)) * 16384 + 8192 + wave * 1024), 16, 0, 0); \
} while (0)
#define STAGE_B(H, U, BUF) do { \
  __builtin_amdgcn_global_load_lds((gptr_t)(Bsrc[H][0] + (U) * 64), \
      (lptr_t)(smem + 65536 + ((BUF) * 2 + (H)) * 16384 + wave * 1024), 16, 0, 0); \
  __builtin_amdgcn_global_load_lds((gptr_t)(Bsrc[H][1] + (U) * 64), \
      (lptr_t)(smem + 65536 + ((BUF) * 2 + (H)) * 16384 + 8192 + wave * 1024), 16, 0, 0); \
} while (0)

  short8 ar0[4], ar1[4], ar2[4], ar3[4];   // A frag sets (issue-early pipeline)
  short8 bfr[2][4];                        // B frags, both k-slices
  floatx4 acc[8][4] = {};

#define LDA(DST, MH, KK, BUF) do { \
  const char* _ab = smem + ((BUF) * 2 + wm) * 16384; \
  _Pragma("unroll") \
  for (int mp = 0; mp < 4; ++mp) { \
    int o = (((MH) * 64 + mp * 16 + l15) * 128 + (KK) * 64 + lhi * 16) ^ rsw; \
    DST[mp] = *(const short8*)(_ab + o); \
  } } while (0)
#define LDB(KK, BUF) do { \
  const char* _bb = smem + 65536 + ((BUF) * 2 + (wn >> 1)) * 16384; \
  _Pragma("unroll") \
  for (int n = 0; n < 4; ++n) { \
    int o = (((wn & 1) * 64 + n * 16 + l15) * 128 + (KK) * 64 + lhi * 16) ^ rsw; \
    bfr[KK][n] = *(const short8*)(_bb + o); \
  } } while (0)

#define MFMA16(MH, KK, FR) do { \
  SP1(); \
  _Pragma("unroll") \
  for (int mp = 0; mp < 4; ++mp) \
    _Pragma("unroll") \
    for (int n = 0; n < 4; ++n) \
      acc[(MH) * 4 + mp][n] = __builtin_amdgcn_mfma_f32_16x16x32_bf16( \
          FR[mp], bfr[KK][n], acc[(MH) * 4 + mp][n], 0, 0, 0); \
  SP0(); \
} while (0)

  // Prologue: A(0)->A[0], B(0)->B[0], B(1)->B[1]   (12 loads, this order).
  STAGE_A(0, 0, 0); STAGE_A(1, 0, 0);
  STAGE_B(0, 0, 0); STAGE_B(1, 0, 0);
  STAGE_B(0, 1, 1); STAGE_B(1, 1, 1);

  for (int u = 0; u < 15; ++u) {
    const int buf = u & 1, nbuf = buf ^ 1;
    STAGE_A(0, u + 1, nbuf); STAGE_A(1, u + 1, nbuf);   // A[nbuf] freed end(u-1)
    WAIT_VM8();                       // A(u),B(u) landed; {B(u+1),A(u+1)} fly
    BARRIER();                        // certify tile u
    LDB(0, buf); LDA(ar0, 0, 0, buf); LDB(1, buf); LDA(ar1, 0, 1, buf);
    WAIT_LGKM8();                     // B0,ar0 retired
    MFMA16(0, 0, ar0);
    LDA(ar2, 1, 0, buf);              // streams under MFMA(0,0)
    WAIT_LGKM4();                     // B1,ar1 retired (ar2 in flight)
    MFMA16(0, 1, ar1);
    BARRIER();                        // B-free: all waves' B reads retired
    if (u < 14) { STAGE_B(0, u + 2, buf); STAGE_B(1, u + 2, buf); }
    LDA(ar3, 1, 1, buf);              // streams under MFMA(0,1)
    WAIT_LGKM4();                     // ar2 retired (ar3 in flight)
    MFMA16(1, 0, ar2);
    WAIT_LGKM0();                     // ar3 retired
    MFMA16(1, 1, ar3);
    BARRIER();                        // A-free
  }
  {  // u = 15 (buf 1): nothing left to stage; natural drain, no barriers.
    WAIT_VM0();
    BARRIER();
    LDB(0, 1); LDA(ar0, 0, 0, 1); LDB(1, 1); LDA(ar1, 0, 1, 1);
    WAIT_LGKM8(); MFMA16(0, 0, ar0);
    LDA(ar2, 1, 0, 1);
    WAIT_LGKM4(); MFMA16(0, 1, ar1);
    LDA(ar3, 1, 1, 1);
    WAIT_LGKM4(); MFMA16(1, 0, ar2);
    WAIT_LGKM0(); MFMA16(1, 1, ar3);
  }

  // Epilogue. C/D layout: col = lane&15, row = (lane>>4)*4 + j. No m-guard:
  // max gm = 32512 + 128 + 112 + 12 + 3 = 32767 < M_REAL.
#pragma unroll
  for (int m = 0; m < 8; ++m)
#pragma unroll
    for (int n = 0; n < 4; ++n) {
      const int gn = n0 + wn * 64 + n * 16 + l15;
      const float bia = bias[gn];
#pragma unroll
      for (int j = 0; j < 4; ++j) {
        const int gm = m0 + wm * 128 + m * 16 + lhi * 4 + j;
        C[(size_t)gm * D_DIM + gn] = acc[m][n][j] + bia;
      }
    }
#undef STAGE_A
#undef STAGE_B
#undef LDA
#undef LDB
#undef MFMA16
}

// ---------------------------------------------------------------------------
// Tail GEMV: out[r,c] for r in [32768, 32776), all 1024 cols.
// ---------------------------------------------------------------------------
__global__ __launch_bounds__(256) void tail_gemv_kernel(
    const ushort* __restrict__ S, const ushort* __restrict__ Wf,
    const float* __restrict__ cvec, float* __restrict__ out)
{
  const int wavei = threadIdx.x >> 6, lane = threadIdx.x & 63;
  const int c = blockIdx.x * 4 + wavei;
  float acc[8] = {};
  for (int i = 0; i < 16; ++i) {
    const int k = i * 64 + lane;
    const float wv = bf2f(Wf[(size_t)c * D_DIM + k]);
#pragma unroll
    for (int r = 0; r < 8; ++r)
      acc[r] += wv * bf2f(S[(size_t)(M_MAIN + r) * D_DIM + k]);
  }
#pragma unroll
  for (int r = 0; r < 8; ++r) {
#pragma unroll
    for (int off = 32; off; off >>= 1) acc[r] += __shfl_xor(acc[r], off, 64);
  }
  if (lane == 0) {
    const float bia = cvec[c];
#pragma unroll
    for (int r = 0; r < 8; ++r)
      out[(size_t)(M_MAIN + r) * D_DIM + c] = acc[r] + bia;
  }
}

// ---------------------------------------------------------------------------
// Small GEMM for Wfused = Wo @ Wv (bf16 out): m97-style 128x128 tile, BK=64.
// ---------------------------------------------------------------------------
__global__ __launch_bounds__(256) void gemm_bt_kernel(
    const ushort* __restrict__ A, const ushort* __restrict__ Bm,
    ushort* __restrict__ Cb, int K, int N)
{
  __shared__ ushort As[128][64];   // 16 KB
  __shared__ ushort Bs[128][64];   // 16 KB
  const int tid  = threadIdx.x;
  const int wave = tid >> 6;
  const int lane = tid & 63;
  const int wm = wave >> 1, wn = wave & 1;
  const int n0 = blockIdx.x * 128, m0 = blockIdx.y * 128;
  const int l15 = lane & 15, lhi = lane >> 4;

  floatx4 acc[4][4] = {};

  const int srow = tid >> 3;
  const int sk8  = (tid & 7) * 8;
  const ushort* Ab = A  + (size_t)(m0 + srow) * K + sk8;
  const ushort* Bb = Bm + (size_t)(n0 + srow) * K + sk8;

  for (int k0 = 0; k0 < K; k0 += 64) {
#pragma unroll
    for (int q = 0; q < 4; ++q)
      __builtin_amdgcn_global_load_lds((gptr_t)(Ab + k0 + (size_t)q * 32 * K),
          (lptr_t)((char*)&As[0][0] + (q * 256 + wave * 64) * 16), 16, 0, 0);
#pragma unroll
    for (int q = 0; q < 4; ++q)
      __builtin_amdgcn_global_load_lds((gptr_t)(Bb + k0 + (size_t)q * 32 * K),
          (lptr_t)((char*)&Bs[0][0] + (q * 256 + wave * 64) * 16), 16, 0, 0);
    __syncthreads();

#pragma unroll
    for (int kk = 0; kk < 2; ++kk) {
      short8 af[4], bfrg[4];
#pragma unroll
      for (int i = 0; i < 4; ++i) {
        af[i]   = *(const short8*)(&As[wm * 64 + i * 16 + l15][kk * 32 + lhi * 8]);
        bfrg[i] = *(const short8*)(&Bs[wn * 64 + i * 16 + l15][kk * 32 + lhi * 8]);
      }
#pragma unroll
      for (int mi = 0; mi < 4; ++mi)
#pragma unroll
        for (int ni = 0; ni < 4; ++ni)
          acc[mi][ni] = __builtin_amdgcn_mfma_f32_16x16x32_bf16(
              af[mi], bfrg[ni], acc[mi][ni], 0, 0, 0);
    }
    __syncthreads();
  }

#pragma unroll
  for (int mi = 0; mi < 4; ++mi)
#pragma unroll
    for (int ni = 0; ni < 4; ++ni) {
      const int gn = n0 + wn * 64 + ni * 16 + l15;
#pragma unroll
      for (int j = 0; j < 4; ++j) {
        const int gm = m0 + wm * 64 + mi * 16 + lhi * 4 + j;
        Cb[(size_t)gm * N + gn] = f2bf(acc[mi][ni][j]);
      }
    }
}

// ---------------------------------------------------------------------------
// Depthwise temporal conv -> s_bf16.
// s[t] = sum_i w[i] x[t-32+i] (x[neg]=0), t in [0,4096].
// Ascending recurrence with batched 32-row register window + exact resync:
//   s[t] = (s[t-1] - w0*x[t-33]) / r + w31*x[t-1]
// Per 32-step group: 32 independent loads batched; resync caps error growth.
// Block = 128 outputs; reads (32+128) rows -> 1.25 reads/output.
// ---------------------------------------------------------------------------
#define CTCH 128
__global__ __launch_bounds__(256) void conv_kernel(
    const float* __restrict__ x, const float* __restrict__ dw,
    ushort* __restrict__ S)
{
  const int b   = blockIdx.y;
  const int col = blockIdx.z * 256 + threadIdx.x;   // 0..1023
  const int t0  = blockIdx.x * CTCH;

  float w[32];                                       // uniform -> scalar regs
#pragma unroll
  for (int i = 0; i < 32; ++i) w[i] = dw[i];
  const float rinv = w[0] / w[1];                    // 1/r
  const float w31  = w[31];
  const float c0   = -w[0] * rinv;                   // -(w0/r)

  const float* xb = x + (size_t)b * T_DIM * D_DIM + col;
  ushort*      Sb = S + (size_t)b * (T_DIM + 1) * D_DIM + col;

  float prev[32], cur[32];
  float s;
  if (blockIdx.x == 0) {
#pragma unroll
    for (int i = 0; i < 32; ++i) prev[i] = 0.f;
    s = 0.f;
    Sb[0] = f2bf(0.f);                               // row t=0
  } else {
#pragma unroll
    for (int i = 0; i < 32; ++i) prev[i] = xb[(size_t)(t0 - 32 + i) * D_DIM];
    s = 0.f;
#pragma unroll
    for (int i = 0; i < 32; ++i) s = __builtin_fmaf(w[i], prev[i], s);
  }

#pragma unroll 1
  for (int g = 0; g < 4; g += 2) {
#pragma unroll
    for (int i = 0; i < 32; ++i) cur[i] = xb[(size_t)(t0 + g * 32 + i) * D_DIM];
#pragma unroll
    for (int j = 0; j < 32; ++j) {
      s = __builtin_fmaf(s, rinv, __builtin_fmaf(prev[j], c0, w31 * cur[j]));
      Sb[(size_t)(t0 + g * 32 + 1 + j) * D_DIM] = f2bf(s);
    }
    s = 0.f;                                         // exact resync from cur
#pragma unroll
    for (int i = 0; i < 32; ++i) s = __builtin_fmaf(w[i], cur[i], s);
#pragma unroll
    for (int i = 0; i < 32; ++i) prev[i] = xb[(size_t)(t0 + (g + 1) * 32 + i) * D_DIM];
#pragma unroll
    for (int j = 0; j < 32; ++j) {
      s = __builtin_fmaf(s, rinv, __builtin_fmaf(cur[j], c0, w31 * prev[j]));
      Sb[(size_t)(t0 + (g + 1) * 32 + 1 + j) * D_DIM] = f2bf(s);
    }
    s = 0.f;
#pragma unroll
    for (int i = 0; i < 32; ++i) s = __builtin_fmaf(w[i], prev[i], s);
  }
}

// Wo fp32 -> bf16 straight copy.
__global__ void convert_wo_kernel(const float* __restrict__ Wo, ushort* __restrict__ WoB) {
  const int i = blockIdx.x * 256 + threadIdx.x;      // float4 index
  const float4 v = ((const float4*)Wo)[i];
  ushort4 o = make_ushort4(f2bf(v.x), f2bf(v.y), f2bf(v.z), f2bf(v.w));
  *(ushort4*)(WoB + (size_t)i * 4) = o;
}

// Wv fp32 -> WvT bf16 (transpose via LDS 32x32 tile).
__global__ void transpose_wv_kernel(const float* __restrict__ Wv, ushort* __restrict__ WvT) {
  __shared__ float tile[32][33];
  const int tx = threadIdx.x;   // 0..31
  const int ty = threadIdx.y;   // 0..7
  const int c0 = blockIdx.x * 32;
  const int r0 = blockIdx.y * 32;
#pragma unroll
  for (int j = 0; j < 4; ++j)
    tile[ty + j * 8][tx] = Wv[(size_t)(r0 + ty + j * 8) * D_DIM + c0 + tx];
  __syncthreads();
#pragma unroll
  for (int j = 0; j < 4; ++j)
    WvT[(size_t)(c0 + ty + j * 8) * D_DIM + r0 + tx] = f2bf(tile[tx][ty + j * 8]);
}

// cvec[j] = sum(dw) * dot(Wo[j,:], bv) + bo[j].  One wave per j.
__global__ void bias_kernel(const float* __restrict__ Wo, const float* __restrict__ bv,
                            const float* __restrict__ bo, const float* __restrict__ dw,
                            float* __restrict__ cvec) {
  const int j    = blockIdx.x * 4 + (threadIdx.x >> 6);
  const int lane = threadIdx.x & 63;
  float sumw = 0.f;
#pragma unroll
  for (int i = 0; i < 32; ++i) sumw += dw[i];
  float s = 0.f;
  for (int k = lane; k < D_DIM; k += 64) s += Wo[(size_t)j * D_DIM + k] * bv[k];
#pragma unroll
  for (int off = 32; off; off >>= 1) s += __shfl_xor(s, off, 64);
  if (lane == 0) cvec[j] = sumw * s + bo[j];
}

// ---------------------------------------------------------------------------
extern "C" void kernel_launch(void* const* d_in, const int* in_sizes, int n_in,
                              void* d_out, int out_size, void* d_ws, size_t ws_size,
                              hipStream_t stream) {
  const float* x  = (const float*)d_in[0];
  const float* Wv = (const float*)d_in[1];
  const float* bv = (const float*)d_in[2];
  const float* Wo = (const float*)d_in[3];
  const float* bo = (const float*)d_in[4];
  const float* dw = (const float*)d_in[5];
  float* out = (float*)d_out;

  // Workspace layout (~73.4 MB total).
  char* ws = (char*)d_ws;
  ushort* S      = (ushort*)ws;                                  // M_REAL*1024 bf16
  ushort* WoB    = (ushort*)(ws + (size_t)M_REAL * D_DIM * 2);   // 1024^2 bf16
  ushort* WvT    = WoB + (size_t)D_DIM * D_DIM;                  // 1024^2 bf16
  ushort* Wfused = WvT + (size_t)D_DIM * D_DIM;                  // 1024^2 bf16
  float*  cvec   = (float*)(Wfused + (size_t)D_DIM * D_DIM);     // 1024 fp32

  // 1) Weight prep (all tiny).
  convert_wo_kernel<<<dim3(D_DIM * D_DIM / 1024), dim3(256), 0, stream>>>(Wo, WoB);
  transpose_wv_kernel<<<dim3(32, 32), dim3(32, 8), 0, stream>>>(Wv, WvT);
  bias_kernel<<<dim3(256), dim3(256), 0, stream>>>(Wo, bv, bo, dw, cvec);

  // 2) Wfused[j,k] = sum_p Wo[j,p] * Wv[p,k]  (row-major bf16).
  gemm_bt_kernel<<<dim3(8, 8), dim3(256), 0, stream>>>(
      WoB, WvT, Wfused, D_DIM, D_DIM);

  // 3) Temporal conv -> s bf16 (batched-window recurrence).
  conv_kernel<<<dim3(T_DIM / CTCH, B_DIM, 4), dim3(256), 0, stream>>>(x, dw, S);

  // 4) out = s @ Wfused^T + cvec  (256^2, issue-early/wait-counted,
  //    XCD-swizzled, exactly 2 rounds of 256 blocks) + 8-row GEMV tail.
  gemm256_kernel<<<dim3(NWG), dim3(512), 0, stream>>>(S, Wfused, out, cvec);
  tail_gemv_kernel<<<dim3(256), dim3(256), 0, stream>>>(S, Wfused, cvec, out);
}